// Round 1
// baseline (870.676 us; speedup 1.0000x reference)
//
#include <hip/hip_runtime.h>
#include <math.h>

#define CIN 256
#define CB 64
#define COUT 256
#define KNB 27
#define EPS 1e-5f
#define LS 68   // LDS row stride (floats): 16B-aligned float4s, conflict-benign

// ---------------------------------------------------------------------------
// GEMM1: t1[N,64] = data[N,256] @ w1a[256,64], accumulate GN1 group sums
// block: 256 threads, tile 64 rows x 64 cols, k in 4 chunks of 64
// ---------------------------------------------------------------------------
__global__ __launch_bounds__(256) void k_gemm1(const float* __restrict__ data,
        const float* __restrict__ w1a, float* __restrict__ t1,
        float* __restrict__ stats, int n)
{
    __shared__ float As[64][LS];
    __shared__ float Bs[64][LS];
    __shared__ float s_sum[32], s_sq[32];
    const int tid = threadIdx.x;
    const int row0 = blockIdx.x * 64;
    if (tid < 32) { s_sum[tid] = 0.f; s_sq[tid] = 0.f; }
    const int ti = tid >> 4, tj = tid & 15;
    float acc[4][4] = {};
    for (int kk = 0; kk < 4; ++kk) {
        __syncthreads();
#pragma unroll
        for (int l = 0; l < 4; ++l) {
            int idx = l * 256 + tid;
            int r = idx >> 4, c4 = idx & 15;
            float4 v = make_float4(0.f, 0.f, 0.f, 0.f);
            if (row0 + r < n)
                v = *(const float4*)(data + (size_t)(row0 + r) * CIN + kk * 64 + c4 * 4);
            *(float4*)(&As[r][c4 * 4]) = v;
            float4 w = *(const float4*)(w1a + (size_t)(kk * 64 + r) * CB + c4 * 4);
            *(float4*)(&Bs[r][c4 * 4]) = w;
        }
        __syncthreads();
#pragma unroll 16
        for (int k = 0; k < 64; ++k) {
            float a[4], b[4];
#pragma unroll
            for (int r = 0; r < 4; ++r) a[r] = As[ti * 4 + r][k];
            float4 bv = *(const float4*)(&Bs[k][tj * 4]);
            b[0] = bv.x; b[1] = bv.y; b[2] = bv.z; b[3] = bv.w;
#pragma unroll
            for (int r = 0; r < 4; ++r)
#pragma unroll
                for (int s = 0; s < 4; ++s) acc[r][s] = fmaf(a[r], b[s], acc[r][s]);
        }
    }
    // store + per-group (2 channels/group) partial stats
    float gs0 = 0.f, gq0 = 0.f, gs1 = 0.f, gq1 = 0.f;
#pragma unroll
    for (int r = 0; r < 4; ++r) {
        int row = row0 + ti * 4 + r;
        if (row < n) {
            *(float4*)(t1 + (size_t)row * CB + tj * 4) =
                make_float4(acc[r][0], acc[r][1], acc[r][2], acc[r][3]);
            gs0 += acc[r][0] + acc[r][1];
            gq0 += acc[r][0] * acc[r][0] + acc[r][1] * acc[r][1];
            gs1 += acc[r][2] + acc[r][3];
            gq1 += acc[r][2] * acc[r][2] + acc[r][3] * acc[r][3];
        }
    }
    atomicAdd(&s_sum[tj * 2 + 0], gs0);
    atomicAdd(&s_sq [tj * 2 + 0], gq0);
    atomicAdd(&s_sum[tj * 2 + 1], gs1);
    atomicAdd(&s_sq [tj * 2 + 1], gq1);
    __syncthreads();
    if (tid < 32) {
        atomicAdd(&stats[tid], s_sum[tid]);
        atomicAdd(&stats[32 + tid], s_sq[tid]);
    }
}

// ---------------------------------------------------------------------------
// GN apply + ReLU for a [N,64] buffer (2 channels per group), in-place.
// st[0:32) = group sums, st[32:64) = group sum-of-squares
// ---------------------------------------------------------------------------
__global__ void k_apply(float* __restrict__ buf, const float* __restrict__ st,
        const float* __restrict__ gamma, const float* __restrict__ beta, int n)
{
    const float cnt = (float)n * 2.0f;
    const int total = n * (CB / 4);
    for (int i = blockIdx.x * blockDim.x + threadIdx.x; i < total;
         i += gridDim.x * blockDim.x) {
        int c4 = (i & (CB / 4 - 1)) * 4;
        int g0 = c4 >> 1;
        int g1 = g0 + 1;
        float mu0 = st[g0] / cnt, mu1 = st[g1] / cnt;
        float v0 = st[32 + g0] / cnt - mu0 * mu0;
        float v1 = st[32 + g1] / cnt - mu1 * mu1;
        float i0 = rsqrtf(v0 + EPS), i1 = rsqrtf(v1 + EPS);
        float4 v = *(float4*)(buf + (size_t)i * 4);
        v.x = fmaxf((v.x - mu0) * i0 * gamma[c4 + 0] + beta[c4 + 0], 0.f);
        v.y = fmaxf((v.y - mu0) * i0 * gamma[c4 + 1] + beta[c4 + 1], 0.f);
        v.z = fmaxf((v.z - mu1) * i1 * gamma[c4 + 2] + beta[c4 + 2], 0.f);
        v.w = fmaxf((v.w - mu1) * i1 * gamma[c4 + 3] + beta[c4 + 3], 0.f);
        *(float4*)(buf + (size_t)i * 4) = v;
    }
}

// ---------------------------------------------------------------------------
// Octree conv: y[n,d] = sum_k sum_c x[neigh[n,k],c] * w3[k,c,d]
// block: 256 threads, 64 nodes; LDS-staged gathered x (transposed) + w3[k];
// accumulates GN2 group sums.
// ---------------------------------------------------------------------------
__global__ __launch_bounds__(256) void k_conv(const float* __restrict__ x,
        const int* __restrict__ neigh, const float* __restrict__ w3,
        float* __restrict__ y, float* __restrict__ stats, int n)
{
    __shared__ float xs[64][LS];    // [c][node]
    __shared__ float wsm[64][LS];   // [c][d]
    __shared__ int s_idx[64 * KNB];
    __shared__ float s_sum[32], s_sq[32];
    const int tid = threadIdx.x;
    const int row0 = blockIdx.x * 64;
    if (tid < 32) { s_sum[tid] = 0.f; s_sq[tid] = 0.f; }
    const long nk = (long)n * KNB;
    for (int j = tid; j < 64 * KNB; j += 256) {
        long g = (long)row0 * KNB + j;
        s_idx[j] = (g < nk) ? neigh[g] : 0;
    }
    const int ti = tid >> 4, tj = tid & 15;
    const int gn  = tid >> 2;          // gather node (0..63)
    const int gc0 = (tid & 3) * 16;    // gather channel start
    float acc[4][4] = {};
    for (int k = 0; k < KNB; ++k) {
        __syncthreads();
        {
            int idx = s_idx[gn * KNB + k];
            const float* src = x + (size_t)idx * CB + gc0;
#pragma unroll
            for (int m = 0; m < 4; ++m) {
                float4 v = *(const float4*)(src + m * 4);
                xs[gc0 + m * 4 + 0][gn] = v.x;
                xs[gc0 + m * 4 + 1][gn] = v.y;
                xs[gc0 + m * 4 + 2][gn] = v.z;
                xs[gc0 + m * 4 + 3][gn] = v.w;
            }
        }
#pragma unroll
        for (int l = 0; l < 4; ++l) {
            int id2 = l * 256 + tid;
            int cr = id2 >> 4, d4 = id2 & 15;
            float4 w = *(const float4*)(w3 + (size_t)k * CB * CB + cr * CB + d4 * 4);
            *(float4*)(&wsm[cr][d4 * 4]) = w;
        }
        __syncthreads();
#pragma unroll 8
        for (int c = 0; c < 64; ++c) {
            float4 av = *(const float4*)(&xs[c][ti * 4]);
            float4 bv = *(const float4*)(&wsm[c][tj * 4]);
            float a[4] = {av.x, av.y, av.z, av.w};
            float b[4] = {bv.x, bv.y, bv.z, bv.w};
#pragma unroll
            for (int r = 0; r < 4; ++r)
#pragma unroll
                for (int s = 0; s < 4; ++s) acc[r][s] = fmaf(a[r], b[s], acc[r][s]);
        }
    }
    float gs0 = 0.f, gq0 = 0.f, gs1 = 0.f, gq1 = 0.f;
#pragma unroll
    for (int r = 0; r < 4; ++r) {
        int row = row0 + ti * 4 + r;
        if (row < n) {
            *(float4*)(y + (size_t)row * CB + tj * 4) =
                make_float4(acc[r][0], acc[r][1], acc[r][2], acc[r][3]);
            gs0 += acc[r][0] + acc[r][1];
            gq0 += acc[r][0] * acc[r][0] + acc[r][1] * acc[r][1];
            gs1 += acc[r][2] + acc[r][3];
            gq1 += acc[r][2] * acc[r][2] + acc[r][3] * acc[r][3];
        }
    }
    atomicAdd(&s_sum[tj * 2 + 0], gs0);
    atomicAdd(&s_sq [tj * 2 + 0], gq0);
    atomicAdd(&s_sum[tj * 2 + 1], gs1);
    atomicAdd(&s_sq [tj * 2 + 1], gq1);
    __syncthreads();
    if (tid < 32) {
        atomicAdd(&stats[64 + tid], s_sum[tid]);
        atomicAdd(&stats[96 + tid], s_sq[tid]);
    }
}

// ---------------------------------------------------------------------------
// GEMM2: z[N,256] = y2[N,64] @ w1b[64,256]  (z -> d_out), GN3 group sums
// grid: (ceil(N/64), 4), block 256; each block: 64 rows x 64 cols, K=64
// ---------------------------------------------------------------------------
__global__ __launch_bounds__(256) void k_gemm2(const float* __restrict__ y2,
        const float* __restrict__ w1b, float* __restrict__ z,
        float* __restrict__ stats, int n)
{
    __shared__ float As[64][LS];
    __shared__ float Bs[64][LS];
    __shared__ float s_sum[8], s_sq[8];
    const int tid = threadIdx.x;
    const int row0 = blockIdx.x * 64;
    const int cb = blockIdx.y;
    if (tid < 8) { s_sum[tid] = 0.f; s_sq[tid] = 0.f; }
#pragma unroll
    for (int l = 0; l < 4; ++l) {
        int idx = l * 256 + tid;
        int r = idx >> 4, c4 = idx & 15;
        float4 v = make_float4(0.f, 0.f, 0.f, 0.f);
        if (row0 + r < n)
            v = *(const float4*)(y2 + (size_t)(row0 + r) * CB + c4 * 4);
        *(float4*)(&As[r][c4 * 4]) = v;
        float4 w = *(const float4*)(w1b + (size_t)r * COUT + cb * 64 + c4 * 4);
        *(float4*)(&Bs[r][c4 * 4]) = w;
    }
    __syncthreads();
    const int ti = tid >> 4, tj = tid & 15;
    float acc[4][4] = {};
#pragma unroll 16
    for (int k = 0; k < 64; ++k) {
        float a[4], b[4];
#pragma unroll
        for (int r = 0; r < 4; ++r) a[r] = As[ti * 4 + r][k];
        float4 bv = *(const float4*)(&Bs[k][tj * 4]);
        b[0] = bv.x; b[1] = bv.y; b[2] = bv.z; b[3] = bv.w;
#pragma unroll
        for (int r = 0; r < 4; ++r)
#pragma unroll
            for (int s = 0; s < 4; ++s) acc[r][s] = fmaf(a[r], b[s], acc[r][s]);
    }
    float gs = 0.f, gq = 0.f;
#pragma unroll
    for (int r = 0; r < 4; ++r) {
        int row = row0 + ti * 4 + r;
        if (row < n) {
            *(float4*)(z + (size_t)row * COUT + cb * 64 + tj * 4) =
                make_float4(acc[r][0], acc[r][1], acc[r][2], acc[r][3]);
#pragma unroll
            for (int s = 0; s < 4; ++s) { gs += acc[r][s]; gq += acc[r][s] * acc[r][s]; }
        }
    }
    atomicAdd(&s_sum[tj >> 1], gs);
    atomicAdd(&s_sq [tj >> 1], gq);
    __syncthreads();
    if (tid < 8) {
        atomicAdd(&stats[128 + cb * 8 + tid], s_sum[tid]);
        atomicAdd(&stats[160 + cb * 8 + tid], s_sq[tid]);
    }
}

// ---------------------------------------------------------------------------
// Final: out = relu(GN3(z) + data), in-place on d_out (z already there)
// ---------------------------------------------------------------------------
__global__ void k_final(float* __restrict__ zo, const float* __restrict__ data,
        const float* __restrict__ st, const float* __restrict__ gamma,
        const float* __restrict__ beta, int n)
{
    const float cnt = (float)n * 8.0f;
    const int total = n * (COUT / 4);
    for (int i = blockIdx.x * blockDim.x + threadIdx.x; i < total;
         i += gridDim.x * blockDim.x) {
        int c4 = (i & (COUT / 4 - 1)) * 4;
        int g = c4 >> 3;
        float mu = st[g] / cnt;
        float var = st[32 + g] / cnt - mu * mu;
        float inv = rsqrtf(var + EPS);
        float4 zv = *(float4*)(zo + (size_t)i * 4);
        float4 dv = *(const float4*)(data + (size_t)i * 4);
        zv.x = fmaxf((zv.x - mu) * inv * gamma[c4 + 0] + beta[c4 + 0] + dv.x, 0.f);
        zv.y = fmaxf((zv.y - mu) * inv * gamma[c4 + 1] + beta[c4 + 1] + dv.y, 0.f);
        zv.z = fmaxf((zv.z - mu) * inv * gamma[c4 + 2] + beta[c4 + 2] + dv.z, 0.f);
        zv.w = fmaxf((zv.w - mu) * inv * gamma[c4 + 3] + beta[c4 + 3] + dv.w, 0.f);
        *(float4*)(zo + (size_t)i * 4) = zv;
    }
}

// ---------------------------------------------------------------------------
extern "C" void kernel_launch(void* const* d_in, const int* in_sizes, int n_in,
                              void* d_out, int out_size, void* d_ws, size_t ws_size,
                              hipStream_t stream)
{
    const float* data = (const float*)d_in[0];
    const int*   neigh = (const int*)d_in[1];
    const float* w1a = (const float*)d_in[2];
    const float* g1a = (const float*)d_in[3];
    const float* b1a = (const float*)d_in[4];
    const float* w3  = (const float*)d_in[5];
    const float* g3  = (const float*)d_in[6];
    const float* b3  = (const float*)d_in[7];
    const float* w1b = (const float*)d_in[8];
    const float* g1b = (const float*)d_in[9];
    const float* b1b = (const float*)d_in[10];
    float* out = (float*)d_out;
    float* ws  = (float*)d_ws;

    const int n = in_sizes[0] / CIN;   // 150000

    // ws layout: stats[192] | pad to 256 | bufA[N*64] | bufB[N*64]
    float* stats = ws;
    float* bufA  = ws + 256;
    float* bufB  = bufA + (size_t)n * CB;

    hipMemsetAsync(stats, 0, 192 * sizeof(float), stream);

    const int nb = (n + 63) / 64;
    k_gemm1<<<nb, 256, 0, stream>>>(data, w1a, bufA, stats, n);
    k_apply<<<2048, 256, 0, stream>>>(bufA, stats, g1a, b1a, n);
    k_conv <<<nb, 256, 0, stream>>>(bufA, neigh, w3, bufB, stats, n);
    k_apply<<<2048, 256, 0, stream>>>(bufB, stats + 64, g3, b3, n);
    k_gemm2<<<dim3(nb, 4), 256, 0, stream>>>(bufB, w1b, out, stats, n);
    k_final<<<2048, 256, 0, stream>>>(out, data, stats + 128, g1b, b1b, n);
}

// Round 2
// 489.493 us; speedup vs baseline: 1.7787x; 1.7787x over previous
//
#include <hip/hip_runtime.h>
#include <math.h>

#define CIN 256
#define CB 64
#define COUT 256
#define KNB 27
#define EPS 1e-5f

typedef unsigned short u16;
typedef __attribute__((ext_vector_type(8))) short short8;
typedef __attribute__((ext_vector_type(4))) float f32x4;

__device__ inline short f2bf(float f) {
    union { float f; unsigned u; } v; v.f = f;
    unsigned r = v.u + 0x7fff + ((v.u >> 16) & 1);   // RNE
    return (short)(r >> 16);
}
__device__ inline float bf2f(short s) {
    union { unsigned u; float f; } v; v.u = ((unsigned)(u16)s) << 16;
    return v.f;
}
__device__ inline short8 pack8(float4 x0, float4 x1) {
    short8 r;
    r[0] = f2bf(x0.x); r[1] = f2bf(x0.y); r[2] = f2bf(x0.z); r[3] = f2bf(x0.w);
    r[4] = f2bf(x1.x); r[5] = f2bf(x1.y); r[6] = f2bf(x1.z); r[7] = f2bf(x1.w);
    return r;
}

// ---------------------------------------------------------------------------
// Weight prep: bf16 conversion + transposes (+ XOR-swizzled w3 LDS image)
//  w1at[d][k]   : [64][256]
//  w3img[k]     : per k an 8KB image, ushort index d*64 + (c ^ ((d&7)<<3))
//  w1bt[d][c]   : [256][64]
// ---------------------------------------------------------------------------
__global__ void k_prep(const float* __restrict__ w1a, const float* __restrict__ w3,
                       const float* __restrict__ w1b, u16* __restrict__ w1at,
                       u16* __restrict__ w3img, u16* __restrict__ w1bt)
{
    int i = blockIdx.x * 256 + threadIdx.x;
    if (i < 16384) {
        int k = i >> 6, d = i & 63;
        w1at[d * 256 + k] = (u16)f2bf(w1a[i]);
    } else if (i < 126976) {
        int j = i - 16384;
        int k = j >> 12, c = (j >> 6) & 63, d = j & 63;
        w3img[(size_t)k * 4096 + d * 64 + (c ^ ((d & 7) << 3))] = (u16)f2bf(w3[j]);
    } else if (i < 143360) {
        int j = i - 126976;
        int c = j >> 8, d = j & 255;
        w1bt[d * 64 + c] = (u16)f2bf(w1b[j]);
    }
}

// ---------------------------------------------------------------------------
// GEMM1: t1[N,64](bf16) = data[N,256](f32->bf16) @ w1a ; GN1 stats
// 4 waves, each wave: 16 rows x 64 cols, K=256 (8 ksteps of 32). No LDS tiles.
// ---------------------------------------------------------------------------
__global__ __launch_bounds__(256) void k_gemm1(const float* __restrict__ data,
        const u16* __restrict__ w1at, u16* __restrict__ t1,
        float* __restrict__ stats, int n)
{
    __shared__ float s_sum[32], s_sq[32];
    const int tid = threadIdx.x;
    if (tid < 32) { s_sum[tid] = 0.f; s_sq[tid] = 0.f; }
    __syncthreads();
    const int l = tid & 63, wv = tid >> 6;
    const int ll = l & 15, lh = l >> 4;
    const int row0 = blockIdx.x * 64;
    const int row = row0 + wv * 16 + ll;
    const int rowc = (row < n) ? row : 0;
    const float* arow = data + (size_t)rowc * CIN + lh * 8;

    f32x4 acc[4] = {};
#pragma unroll
    for (int kc = 0; kc < 8; ++kc) {
        float4 x0 = *(const float4*)(arow + kc * 32);
        float4 x1 = *(const float4*)(arow + kc * 32 + 4);
        short8 a = pack8(x0, x1);
#pragma unroll
        for (int f = 0; f < 4; ++f) {
            short8 b = *(const short8*)(w1at + (size_t)(f * 16 + ll) * 256 + kc * 32 + lh * 8);
            acc[f] = __builtin_amdgcn_mfma_f32_16x16x32_bf16(a, b, acc[f], 0, 0, 0);
        }
    }
    float gs[4] = {0.f, 0.f, 0.f, 0.f}, gq[4] = {0.f, 0.f, 0.f, 0.f};
#pragma unroll
    for (int f = 0; f < 4; ++f) {
#pragma unroll
        for (int r = 0; r < 4; ++r) {
            int rr = row0 + wv * 16 + lh * 4 + r;
            if (rr < n) {
                float v = acc[f][r];
                t1[(size_t)rr * CB + f * 16 + ll] = (u16)f2bf(v);
                gs[f] += v; gq[f] += v * v;
            }
        }
    }
#pragma unroll
    for (int f = 0; f < 4; ++f) {
        atomicAdd(&s_sum[(f * 16 + ll) >> 1], gs[f]);
        atomicAdd(&s_sq [(f * 16 + ll) >> 1], gq[f]);
    }
    __syncthreads();
    if (tid < 32) {
        atomicAdd(&stats[tid], s_sum[tid]);
        atomicAdd(&stats[32 + tid], s_sq[tid]);
    }
}

// ---------------------------------------------------------------------------
// GN apply + ReLU, in-place on a [N,64] bf16 buffer (2 channels per group)
// ---------------------------------------------------------------------------
__global__ void k_apply64(u16* __restrict__ buf, const float* __restrict__ st,
        const float* __restrict__ gamma, const float* __restrict__ beta, int n)
{
    const float cnt = (float)n * 2.0f;
    const int total = n * 8;   // short8 chunks
    for (int i = blockIdx.x * blockDim.x + threadIdx.x; i < total;
         i += gridDim.x * blockDim.x) {
        int c0 = (i & 7) * 8;
        short8 v = ((short8*)buf)[i];
#pragma unroll
        for (int j = 0; j < 8; ++j) {
            int c = c0 + j, g = c >> 1;
            float mu = st[g] / cnt;
            float var = st[32 + g] / cnt - mu * mu;
            float inv = rsqrtf(var + EPS);
            float x = bf2f(v[j]);
            x = fmaxf((x - mu) * inv * gamma[c] + beta[c], 0.f);
            v[j] = f2bf(x);
        }
        ((short8*)buf)[i] = v;
    }
}

// ---------------------------------------------------------------------------
// Octree conv (bf16 MFMA): y[n,d] = sum_k sum_c x[neigh[n,k],c] * w3[k,c,d]
// 64 nodes x 64 d per block; per k: stage swizzled w3[k] (8KB) to LDS,
// per-lane 16B gathers of x rows -> A frags, 8 MFMA per wave. GN2 stats.
// ---------------------------------------------------------------------------
__global__ __launch_bounds__(256) void k_conv(const u16* __restrict__ xb,
        const int* __restrict__ neigh, const u16* __restrict__ w3img,
        u16* __restrict__ y, float* __restrict__ stats, int n)
{
    __shared__ u16 s_w3[4096];        // 8 KB swizzled [64d][64c] image
    __shared__ int s_idx[64 * KNB];
    __shared__ float s_sum[32], s_sq[32];
    const int tid = threadIdx.x;
    if (tid < 32) { s_sum[tid] = 0.f; s_sq[tid] = 0.f; }
    const int row0 = blockIdx.x * 64;
    for (int j = tid; j < 64 * KNB; j += 256) {
        int node = row0 + j / KNB;
        s_idx[j] = (node < n) ? neigh[(size_t)row0 * KNB + j] : 0;
    }
    const int l = tid & 63, wv = tid >> 6;
    const int ll = l & 15, lh = l >> 4;
    const int node27 = (wv * 16 + ll) * KNB;

    f32x4 acc[4] = {};
    for (int k = 0; k < KNB; ++k) {
        __syncthreads();           // prev-iter B reads done; (k=0: idx staged)
        // stage w3[k]: 256 threads x 32B linear copy (swizzle pre-baked)
        {
            const short8* src = (const short8*)(w3img + (size_t)k * 4096);
            short8 v0 = src[tid * 2];
            short8 v1 = src[tid * 2 + 1];
            ((short8*)s_w3)[tid * 2] = v0;
            ((short8*)s_w3)[tid * 2 + 1] = v1;
        }
        int idx = s_idx[node27 + k];
        const u16* xr = xb + (size_t)idx * CB + lh * 8;
        short8 a0 = *(const short8*)(xr);        // c in [lh*8, lh*8+8)
        short8 a1 = *(const short8*)(xr + 32);   // c in [32+lh*8, ...)
        __syncthreads();
#pragma unroll
        for (int f = 0; f < 4; ++f) {
            int d = f * 16 + ll;
            int swz = (d & 7) << 4;
            short8 b0 = *(const short8*)((const char*)s_w3 + d * 128 + ((lh * 16) ^ swz));
            short8 b1 = *(const short8*)((const char*)s_w3 + d * 128 + ((64 + lh * 16) ^ swz));
            acc[f] = __builtin_amdgcn_mfma_f32_16x16x32_bf16(a0, b0, acc[f], 0, 0, 0);
            acc[f] = __builtin_amdgcn_mfma_f32_16x16x32_bf16(a1, b1, acc[f], 0, 0, 0);
        }
    }
    float gs[4] = {0.f, 0.f, 0.f, 0.f}, gq[4] = {0.f, 0.f, 0.f, 0.f};
#pragma unroll
    for (int f = 0; f < 4; ++f) {
#pragma unroll
        for (int r = 0; r < 4; ++r) {
            int rr = row0 + wv * 16 + lh * 4 + r;
            if (rr < n) {
                float v = acc[f][r];
                y[(size_t)rr * CB + f * 16 + ll] = (u16)f2bf(v);
                gs[f] += v; gq[f] += v * v;
            }
        }
    }
#pragma unroll
    for (int f = 0; f < 4; ++f) {
        atomicAdd(&s_sum[(f * 16 + ll) >> 1], gs[f]);
        atomicAdd(&s_sq [(f * 16 + ll) >> 1], gq[f]);
    }
    __syncthreads();
    if (tid < 32) {
        atomicAdd(&stats[64 + tid], s_sum[tid]);
        atomicAdd(&stats[96 + tid], s_sq[tid]);
    }
}

// ---------------------------------------------------------------------------
// GEMM2: z[N,256](f32,->d_out) = y2[N,64](bf16) @ w1b ; GN3 stats
// grid (nb, 4): 64 rows x 64 cols per block, K=64 (2 ksteps). No LDS tiles.
// ---------------------------------------------------------------------------
__global__ __launch_bounds__(256) void k_gemm2(const u16* __restrict__ y2,
        const u16* __restrict__ w1bt, float* __restrict__ z,
        float* __restrict__ stats, int n)
{
    __shared__ float s_sum[8], s_sq[8];
    const int tid = threadIdx.x;
    if (tid < 8) { s_sum[tid] = 0.f; s_sq[tid] = 0.f; }
    __syncthreads();
    const int l = tid & 63, wv = tid >> 6;
    const int ll = l & 15, lh = l >> 4;
    const int row0 = blockIdx.x * 64;
    const int cb = blockIdx.y;
    const int row = row0 + wv * 16 + ll;
    const int rowc = (row < n) ? row : 0;
    const u16* ar = y2 + (size_t)rowc * CB + lh * 8;
    short8 a0 = *(const short8*)(ar);
    short8 a1 = *(const short8*)(ar + 32);

    f32x4 acc[4] = {};
#pragma unroll
    for (int f = 0; f < 4; ++f) {
        const u16* br = w1bt + (size_t)(cb * 64 + f * 16 + ll) * CB + lh * 8;
        short8 b0 = *(const short8*)(br);
        short8 b1 = *(const short8*)(br + 32);
        acc[f] = __builtin_amdgcn_mfma_f32_16x16x32_bf16(a0, b0, acc[f], 0, 0, 0);
        acc[f] = __builtin_amdgcn_mfma_f32_16x16x32_bf16(a1, b1, acc[f], 0, 0, 0);
    }
    float gs[4] = {0.f, 0.f, 0.f, 0.f}, gq[4] = {0.f, 0.f, 0.f, 0.f};
#pragma unroll
    for (int f = 0; f < 4; ++f) {
#pragma unroll
        for (int r = 0; r < 4; ++r) {
            int rr = row0 + wv * 16 + lh * 4 + r;
            if (rr < n) {
                float v = acc[f][r];
                z[(size_t)rr * COUT + cb * 64 + f * 16 + ll] = v;
                gs[f] += v; gq[f] += v * v;
            }
        }
    }
#pragma unroll
    for (int f = 0; f < 4; ++f) {
        atomicAdd(&s_sum[(f * 16 + ll) >> 3], gs[f]);
        atomicAdd(&s_sq [(f * 16 + ll) >> 3], gq[f]);
    }
    __syncthreads();
    if (tid < 8) {
        atomicAdd(&stats[128 + cb * 8 + tid], s_sum[tid]);
        atomicAdd(&stats[160 + cb * 8 + tid], s_sq[tid]);
    }
}

// ---------------------------------------------------------------------------
// Final: out = relu(GN3(z) + data), in-place on d_out
// ---------------------------------------------------------------------------
__global__ void k_final(float* __restrict__ zo, const float* __restrict__ data,
        const float* __restrict__ st, const float* __restrict__ gamma,
        const float* __restrict__ beta, int n)
{
    const float cnt = (float)n * 8.0f;
    const int total = n * (COUT / 4);
    for (int i = blockIdx.x * blockDim.x + threadIdx.x; i < total;
         i += gridDim.x * blockDim.x) {
        int c4 = (i & (COUT / 4 - 1)) * 4;
        int g = c4 >> 3;
        float mu = st[g] / cnt;
        float var = st[32 + g] / cnt - mu * mu;
        float inv = rsqrtf(var + EPS);
        float4 zv = *(float4*)(zo + (size_t)i * 4);
        float4 dv = *(const float4*)(data + (size_t)i * 4);
        zv.x = fmaxf((zv.x - mu) * inv * gamma[c4 + 0] + beta[c4 + 0] + dv.x, 0.f);
        zv.y = fmaxf((zv.y - mu) * inv * gamma[c4 + 1] + beta[c4 + 1] + dv.y, 0.f);
        zv.z = fmaxf((zv.z - mu) * inv * gamma[c4 + 2] + beta[c4 + 2] + dv.z, 0.f);
        zv.w = fmaxf((zv.w - mu) * inv * gamma[c4 + 3] + beta[c4 + 3] + dv.w, 0.f);
        *(float4*)(zo + (size_t)i * 4) = zv;
    }
}

// ---------------------------------------------------------------------------
extern "C" void kernel_launch(void* const* d_in, const int* in_sizes, int n_in,
                              void* d_out, int out_size, void* d_ws, size_t ws_size,
                              hipStream_t stream)
{
    const float* data = (const float*)d_in[0];
    const int*   neigh = (const int*)d_in[1];
    const float* w1a = (const float*)d_in[2];
    const float* g1a = (const float*)d_in[3];
    const float* b1a = (const float*)d_in[4];
    const float* w3  = (const float*)d_in[5];
    const float* g3  = (const float*)d_in[6];
    const float* b3  = (const float*)d_in[7];
    const float* w1b = (const float*)d_in[8];
    const float* g1b = (const float*)d_in[9];
    const float* b1b = (const float*)d_in[10];
    float* out = (float*)d_out;
    float* ws  = (float*)d_ws;

    const int n = in_sizes[0] / CIN;   // 150000

    // ws layout: stats[192] (pad 256 f32) | w1at[16384] | w3img[110592] |
    //            w1bt[16384] | t1[N*64] bf16 | y[N*64] bf16
    float* stats = ws;
    u16* w1at  = (u16*)(ws + 256);
    u16* w3img = w1at + 16384;
    u16* w1bt  = w3img + 110592;
    u16* t1    = w1bt + 16384;
    u16* ybuf  = t1 + (size_t)n * CB;

    hipMemsetAsync(stats, 0, 192 * sizeof(float), stream);

    const int nb = (n + 63) / 64;
    k_prep<<<560, 256, 0, stream>>>(w1a, w3, w1b, w1at, w3img, w1bt);
    k_gemm1<<<nb, 256, 0, stream>>>(data, w1at, t1, stats, n);
    k_apply64<<<2048, 256, 0, stream>>>(t1, stats, g1a, b1a, n);
    k_conv<<<nb, 256, 0, stream>>>(t1, neigh, w3img, ybuf, stats, n);
    k_apply64<<<2048, 256, 0, stream>>>(ybuf, stats + 64, g3, b3, n);
    k_gemm2<<<dim3(nb, 4), 256, 0, stream>>>(ybuf, w1bt, out, stats, n);
    k_final<<<2048, 256, 0, stream>>>(out, data, stats + 128, g1b, b1b, n);
}

// Round 3
// 315.455 us; speedup vs baseline: 2.7601x; 1.5517x over previous
//
#include <hip/hip_runtime.h>
#include <math.h>

#define CIN 256
#define CB 64
#define COUT 256
#define KNB 27
#define EPS 1e-5f

typedef unsigned short u16;
typedef __attribute__((ext_vector_type(8))) short short8;
typedef __attribute__((ext_vector_type(4))) float f32x4;

__device__ inline short f2bf(float f) {
    union { float f; unsigned u; } v; v.f = f;
    unsigned r = v.u + 0x7fff + ((v.u >> 16) & 1);   // RNE
    return (short)(r >> 16);
}
__device__ inline float bf2f(short s) {
    union { unsigned u; float f; } v; v.u = ((unsigned)(u16)s) << 16;
    return v.f;
}
__device__ inline short8 pack8(float4 x0, float4 x1) {
    short8 r;
    r[0] = f2bf(x0.x); r[1] = f2bf(x0.y); r[2] = f2bf(x0.z); r[3] = f2bf(x0.w);
    r[4] = f2bf(x1.x); r[5] = f2bf(x1.y); r[6] = f2bf(x1.z); r[7] = f2bf(x1.w);
    return r;
}

// ---------------------------------------------------------------------------
// Weight prep: bf16 conversion + transposes (+ XOR-swizzled w3 LDS image)
//  w1at[d][k]   : [64][256]
//  w3img[k]     : per k an 8KB image, ushort index d*64 + (c ^ ((d&7)<<3))
//  w1bt[d][c]   : [256][64]
// ---------------------------------------------------------------------------
__global__ void k_prep(const float* __restrict__ w1a, const float* __restrict__ w3,
                       const float* __restrict__ w1b, u16* __restrict__ w1at,
                       u16* __restrict__ w3img, u16* __restrict__ w1bt)
{
    int i = blockIdx.x * 256 + threadIdx.x;
    if (i < 16384) {
        int k = i >> 6, d = i & 63;
        w1at[d * 256 + k] = (u16)f2bf(w1a[i]);
    } else if (i < 126976) {
        int j = i - 16384;
        int k = j >> 12, c = (j >> 6) & 63, d = j & 63;
        w3img[(size_t)k * 4096 + d * 64 + (c ^ ((d & 7) << 3))] = (u16)f2bf(w3[j]);
    } else if (i < 143360) {
        int j = i - 126976;
        int c = j >> 8, d = j & 255;
        w1bt[d * 64 + c] = (u16)f2bf(w1b[j]);
    }
}

// ---------------------------------------------------------------------------
// GEMM1: t1[N,64](bf16) = data[N,256](f32->bf16) @ w1a ; GN1 stats
// 4 waves x (64 rows x 64 cols) per block = 256 rows/block, K=256.
// Stats: shuffle-reduce {1,16,32} -> few LDS atomics -> 32 global/block.
// ---------------------------------------------------------------------------
__global__ __launch_bounds__(256) void k_gemm1(const float* __restrict__ data,
        const u16* __restrict__ w1at, u16* __restrict__ t1,
        float* __restrict__ stats, int n)
{
    __shared__ float s_sum[32], s_sq[32];
    const int tid = threadIdx.x;
    if (tid < 32) { s_sum[tid] = 0.f; s_sq[tid] = 0.f; }
    __syncthreads();
    const int l = tid & 63, wv = tid >> 6;
    const int ll = l & 15, lh = l >> 4;
    const int rowbase = blockIdx.x * 256 + wv * 64;

    f32x4 acc[4][4] = {};
#pragma unroll
    for (int kc = 0; kc < 8; ++kc) {
        short8 b[4];
#pragma unroll
        for (int f = 0; f < 4; ++f)
            b[f] = *(const short8*)(w1at + (size_t)(f * 16 + ll) * 256 + kc * 32 + lh * 8);
#pragma unroll
        for (int rt = 0; rt < 4; ++rt) {
            int row = rowbase + rt * 16 + ll;
            int rowc = (row < n) ? row : 0;
            const float* ar = data + (size_t)rowc * CIN + kc * 32 + lh * 8;
            short8 a = pack8(*(const float4*)ar, *(const float4*)(ar + 4));
#pragma unroll
            for (int f = 0; f < 4; ++f)
                acc[rt][f] = __builtin_amdgcn_mfma_f32_16x16x32_bf16(a, b[f], acc[rt][f], 0, 0, 0);
        }
    }
    float gs[4] = {0.f, 0.f, 0.f, 0.f}, gq[4] = {0.f, 0.f, 0.f, 0.f};
#pragma unroll
    for (int rt = 0; rt < 4; ++rt) {
#pragma unroll
        for (int f = 0; f < 4; ++f) {
#pragma unroll
            for (int r = 0; r < 4; ++r) {
                int rr = rowbase + rt * 16 + lh * 4 + r;
                if (rr < n) {
                    float v = acc[rt][f][r];
                    t1[(size_t)rr * CB + f * 16 + ll] = (u16)f2bf(v);
                    gs[f] += v; gq[f] += v * v;
                }
            }
        }
    }
#pragma unroll
    for (int f = 0; f < 4; ++f) {
        float s = gs[f], q = gq[f];
        s += __shfl_xor(s, 1); s += __shfl_xor(s, 16); s += __shfl_xor(s, 32);
        q += __shfl_xor(q, 1); q += __shfl_xor(q, 16); q += __shfl_xor(q, 32);
        if ((l & 0x31) == 0) {          // ll even, lh==0
            atomicAdd(&s_sum[f * 8 + (ll >> 1)], s);
            atomicAdd(&s_sq [f * 8 + (ll >> 1)], q);
        }
    }
    __syncthreads();
    if (tid < 32) {
        atomicAdd(&stats[tid], s_sum[tid]);
        atomicAdd(&stats[32 + tid], s_sq[tid]);
    }
}

// ---------------------------------------------------------------------------
// GN apply + ReLU, in-place on a [N,64] bf16 buffer (2 channels per group)
// ---------------------------------------------------------------------------
__global__ void k_apply64(u16* __restrict__ buf, const float* __restrict__ st,
        const float* __restrict__ gamma, const float* __restrict__ beta, int n)
{
    const float cnt = (float)n * 2.0f;
    const int total = n * 8;   // short8 chunks
    for (int i = blockIdx.x * blockDim.x + threadIdx.x; i < total;
         i += gridDim.x * blockDim.x) {
        int c0 = (i & 7) * 8;
        short8 v = ((short8*)buf)[i];
#pragma unroll
        for (int j = 0; j < 8; ++j) {
            int c = c0 + j, g = c >> 1;
            float mu = st[g] / cnt;
            float var = st[32 + g] / cnt - mu * mu;
            float inv = rsqrtf(var + EPS);
            float x = bf2f(v[j]);
            x = fmaxf((x - mu) * inv * gamma[c] + beta[c], 0.f);
            v[j] = f2bf(x);
        }
        ((short8*)buf)[i] = v;
    }
}

// ---------------------------------------------------------------------------
// Octree conv (bf16 MFMA): y[n,d] = sum_k sum_c x[neigh[n,k],c] * w3[k,c,d]
// 64 nodes x 64 d per block. Double-buffered swizzled w3 LDS image (one
// barrier per k) + A-gather prefetch of k+1 before computing k. GN2 stats
// via shuffle reduction.
// ---------------------------------------------------------------------------
__global__ __launch_bounds__(256) void k_conv(const u16* __restrict__ xb,
        const int* __restrict__ neigh, const u16* __restrict__ w3img,
        u16* __restrict__ y, float* __restrict__ stats, int n)
{
    __shared__ u16 s_w3[2][4096];     // 2 x 8 KB swizzled [64d][64c] images
    __shared__ int s_idx[64 * KNB];
    __shared__ float s_sum[32], s_sq[32];
    const int tid = threadIdx.x;
    if (tid < 32) { s_sum[tid] = 0.f; s_sq[tid] = 0.f; }
    const int row0 = blockIdx.x * 64;
    for (int j = tid; j < 64 * KNB; j += 256) {
        int node = row0 + j / KNB;
        s_idx[j] = (node < n) ? neigh[(size_t)row0 * KNB + j] : 0;
    }
    const int l = tid & 63, wv = tid >> 6;
    const int ll = l & 15, lh = l >> 4;
    const int node27 = (wv * 16 + ll) * KNB;

    // prologue: stage w3[0] into buffer 0
    {
        const short8* src = (const short8*)(w3img);
        short8 v0 = src[tid * 2], v1 = src[tid * 2 + 1];
        ((short8*)&s_w3[0][0])[tid * 2] = v0;
        ((short8*)&s_w3[0][0])[tid * 2 + 1] = v1;
    }
    __syncthreads();
    short8 a0c, a1c;
    {
        int idx = s_idx[node27];
        const u16* xr = xb + (size_t)idx * CB + lh * 8;
        a0c = *(const short8*)(xr);
        a1c = *(const short8*)(xr + 32);
    }

    f32x4 acc[4] = {};
    for (int k = 0; k < KNB; ++k) {
        const int cur = k & 1;
        short8 a0n, a1n;
        if (k + 1 < KNB) {
            // stage w3[k+1] into the other buffer (linear, swizzle pre-baked)
            const short8* src = (const short8*)(w3img + (size_t)(k + 1) * 4096);
            short8 v0 = src[tid * 2], v1 = src[tid * 2 + 1];
            ((short8*)&s_w3[cur ^ 1][0])[tid * 2] = v0;
            ((short8*)&s_w3[cur ^ 1][0])[tid * 2 + 1] = v1;
            // prefetch next gather
            int idx = s_idx[node27 + k + 1];
            const u16* xr = xb + (size_t)idx * CB + lh * 8;
            a0n = *(const short8*)(xr);
            a1n = *(const short8*)(xr + 32);
        }
#pragma unroll
        for (int f = 0; f < 4; ++f) {
            int d = f * 16 + ll;
            int swz = (d & 7) << 4;
            short8 b0 = *(const short8*)((const char*)&s_w3[cur][0] + d * 128 + ((lh * 16) ^ swz));
            short8 b1 = *(const short8*)((const char*)&s_w3[cur][0] + d * 128 + ((64 + lh * 16) ^ swz));
            acc[f] = __builtin_amdgcn_mfma_f32_16x16x32_bf16(a0c, b0, acc[f], 0, 0, 0);
            acc[f] = __builtin_amdgcn_mfma_f32_16x16x32_bf16(a1c, b1, acc[f], 0, 0, 0);
        }
        __syncthreads();
        a0c = a0n; a1c = a1n;
    }
    float gs[4] = {0.f, 0.f, 0.f, 0.f}, gq[4] = {0.f, 0.f, 0.f, 0.f};
#pragma unroll
    for (int f = 0; f < 4; ++f) {
#pragma unroll
        for (int r = 0; r < 4; ++r) {
            int rr = row0 + wv * 16 + lh * 4 + r;
            if (rr < n) {
                float v = acc[f][r];
                y[(size_t)rr * CB + f * 16 + ll] = (u16)f2bf(v);
                gs[f] += v; gq[f] += v * v;
            }
        }
    }
#pragma unroll
    for (int f = 0; f < 4; ++f) {
        float s = gs[f], q = gq[f];
        s += __shfl_xor(s, 1); s += __shfl_xor(s, 16); s += __shfl_xor(s, 32);
        q += __shfl_xor(q, 1); q += __shfl_xor(q, 16); q += __shfl_xor(q, 32);
        if ((l & 0x31) == 0) {
            atomicAdd(&s_sum[f * 8 + (ll >> 1)], s);
            atomicAdd(&s_sq [f * 8 + (ll >> 1)], q);
        }
    }
    __syncthreads();
    if (tid < 32) {
        atomicAdd(&stats[64 + tid], s_sum[tid]);
        atomicAdd(&stats[96 + tid], s_sq[tid]);
    }
}

// ---------------------------------------------------------------------------
// GEMM2: z[N,256](f32 -> d_out) = y2[N,64](bf16) @ w1b ; GN3 stats
// grid (ceil(N/256), 4): 4 waves x (64 rows x 64 cols), K=64. B hoisted.
// ---------------------------------------------------------------------------
__global__ __launch_bounds__(256) void k_gemm2(const u16* __restrict__ y2,
        const u16* __restrict__ w1bt, float* __restrict__ z,
        float* __restrict__ stats, int n)
{
    __shared__ float s_sum[8], s_sq[8];
    const int tid = threadIdx.x;
    if (tid < 8) { s_sum[tid] = 0.f; s_sq[tid] = 0.f; }
    __syncthreads();
    const int l = tid & 63, wv = tid >> 6;
    const int ll = l & 15, lh = l >> 4;
    const int rowbase = blockIdx.x * 256 + wv * 64;
    const int cb = blockIdx.y;

    short8 b0[4], b1[4];
#pragma unroll
    for (int f = 0; f < 4; ++f) {
        const u16* br = w1bt + (size_t)(cb * 64 + f * 16 + ll) * CB + lh * 8;
        b0[f] = *(const short8*)(br);
        b1[f] = *(const short8*)(br + 32);
    }
    f32x4 acc[4][4] = {};
#pragma unroll
    for (int rt = 0; rt < 4; ++rt) {
        int row = rowbase + rt * 16 + ll;
        int rowc = (row < n) ? row : 0;
        const u16* ar = y2 + (size_t)rowc * CB + lh * 8;
        short8 a0 = *(const short8*)(ar);
        short8 a1 = *(const short8*)(ar + 32);
#pragma unroll
        for (int f = 0; f < 4; ++f) {
            acc[rt][f] = __builtin_amdgcn_mfma_f32_16x16x32_bf16(a0, b0[f], acc[rt][f], 0, 0, 0);
            acc[rt][f] = __builtin_amdgcn_mfma_f32_16x16x32_bf16(a1, b1[f], acc[rt][f], 0, 0, 0);
        }
    }
    float gs[4] = {0.f, 0.f, 0.f, 0.f}, gq[4] = {0.f, 0.f, 0.f, 0.f};
#pragma unroll
    for (int rt = 0; rt < 4; ++rt) {
#pragma unroll
        for (int f = 0; f < 4; ++f) {
#pragma unroll
            for (int r = 0; r < 4; ++r) {
                int rr = rowbase + rt * 16 + lh * 4 + r;
                if (rr < n) {
                    float v = acc[rt][f][r];
                    z[(size_t)rr * COUT + cb * 64 + f * 16 + ll] = v;
                    gs[f] += v; gq[f] += v * v;
                }
            }
        }
    }
#pragma unroll
    for (int f = 0; f < 4; ++f) {
        float s = gs[f], q = gq[f];
        s += __shfl_xor(s, 1); s += __shfl_xor(s, 2); s += __shfl_xor(s, 4);
        s += __shfl_xor(s, 16); s += __shfl_xor(s, 32);
        q += __shfl_xor(q, 1); q += __shfl_xor(q, 2); q += __shfl_xor(q, 4);
        q += __shfl_xor(q, 16); q += __shfl_xor(q, 32);
        if ((l & 0x37) == 0) {          // l==0 (grp f*2) or l==8 (grp f*2+1)
            atomicAdd(&s_sum[f * 2 + (ll >> 3)], s);
            atomicAdd(&s_sq [f * 2 + (ll >> 3)], q);
        }
    }
    __syncthreads();
    if (tid < 8) {
        atomicAdd(&stats[128 + cb * 8 + tid], s_sum[tid]);
        atomicAdd(&stats[160 + cb * 8 + tid], s_sq[tid]);
    }
}

// ---------------------------------------------------------------------------
// Final: out = relu(GN3(z) + data), in-place on d_out
// ---------------------------------------------------------------------------
__global__ void k_final(float* __restrict__ zo, const float* __restrict__ data,
        const float* __restrict__ st, const float* __restrict__ gamma,
        const float* __restrict__ beta, int n)
{
    const float cnt = (float)n * 8.0f;
    const int total = n * (COUT / 4);
    for (int i = blockIdx.x * blockDim.x + threadIdx.x; i < total;
         i += gridDim.x * blockDim.x) {
        int c4 = (i & (COUT / 4 - 1)) * 4;
        int g = c4 >> 3;
        float mu = st[g] / cnt;
        float var = st[32 + g] / cnt - mu * mu;
        float inv = rsqrtf(var + EPS);
        float4 zv = *(float4*)(zo + (size_t)i * 4);
        float4 dv = *(const float4*)(data + (size_t)i * 4);
        zv.x = fmaxf((zv.x - mu) * inv * gamma[c4 + 0] + beta[c4 + 0] + dv.x, 0.f);
        zv.y = fmaxf((zv.y - mu) * inv * gamma[c4 + 1] + beta[c4 + 1] + dv.y, 0.f);
        zv.z = fmaxf((zv.z - mu) * inv * gamma[c4 + 2] + beta[c4 + 2] + dv.z, 0.f);
        zv.w = fmaxf((zv.w - mu) * inv * gamma[c4 + 3] + beta[c4 + 3] + dv.w, 0.f);
        *(float4*)(zo + (size_t)i * 4) = zv;
    }
}

// ---------------------------------------------------------------------------
extern "C" void kernel_launch(void* const* d_in, const int* in_sizes, int n_in,
                              void* d_out, int out_size, void* d_ws, size_t ws_size,
                              hipStream_t stream)
{
    const float* data = (const float*)d_in[0];
    const int*   neigh = (const int*)d_in[1];
    const float* w1a = (const float*)d_in[2];
    const float* g1a = (const float*)d_in[3];
    const float* b1a = (const float*)d_in[4];
    const float* w3  = (const float*)d_in[5];
    const float* g3  = (const float*)d_in[6];
    const float* b3  = (const float*)d_in[7];
    const float* w1b = (const float*)d_in[8];
    const float* g1b = (const float*)d_in[9];
    const float* b1b = (const float*)d_in[10];
    float* out = (float*)d_out;
    float* ws  = (float*)d_ws;

    const int n = in_sizes[0] / CIN;   // 150000

    // ws layout: stats[192] (pad 256 f32) | w1at[16384] | w3img[110592] |
    //            w1bt[16384] | t1[N*64] bf16 | y[N*64] bf16
    float* stats = ws;
    u16* w1at  = (u16*)(ws + 256);
    u16* w3img = w1at + 16384;
    u16* w1bt  = w3img + 110592;
    u16* t1    = w1bt + 16384;
    u16* ybuf  = t1 + (size_t)n * CB;

    hipMemsetAsync(stats, 0, 192 * sizeof(float), stream);

    const int nb64  = (n + 63) / 64;
    const int nb256 = (n + 255) / 256;
    k_prep<<<560, 256, 0, stream>>>(w1a, w3, w1b, w1at, w3img, w1bt);
    k_gemm1<<<nb256, 256, 0, stream>>>(data, w1at, t1, stats, n);
    k_apply64<<<2048, 256, 0, stream>>>(t1, stats, g1a, b1a, n);
    k_conv<<<nb64, 256, 0, stream>>>(t1, neigh, w3img, ybuf, stats, n);
    k_apply64<<<2048, 256, 0, stream>>>(ybuf, stats + 64, g3, b3, n);
    k_gemm2<<<dim3(nb256, 4), 256, 0, stream>>>(ybuf, w1bt, out, stats, n);
    k_final<<<2048, 256, 0, stream>>>(out, data, stats + 128, g1b, b1b, n);
}

// Round 4
// 296.397 us; speedup vs baseline: 2.9375x; 1.0643x over previous
//
#include <hip/hip_runtime.h>
#include <math.h>

#define CIN 256
#define CB 64
#define COUT 256
#define KNB 27
#define EPS 1e-5f

typedef unsigned short u16;
typedef __attribute__((ext_vector_type(8))) short short8;
typedef __attribute__((ext_vector_type(4))) float f32x4;

__device__ inline short f2bf(float f) {
    union { float f; unsigned u; } v; v.f = f;
    unsigned r = v.u + 0x7fff + ((v.u >> 16) & 1);   // RNE
    return (short)(r >> 16);
}
__device__ inline float bf2f(short s) {
    union { unsigned u; float f; } v; v.u = ((unsigned)(u16)s) << 16;
    return v.f;
}
__device__ inline short8 pack8(float4 x0, float4 x1) {
    short8 r;
    r[0] = f2bf(x0.x); r[1] = f2bf(x0.y); r[2] = f2bf(x0.z); r[3] = f2bf(x0.w);
    r[4] = f2bf(x1.x); r[5] = f2bf(x1.y); r[6] = f2bf(x1.z); r[7] = f2bf(x1.w);
    return r;
}

// ---------------------------------------------------------------------------
// Weight prep: bf16 conversion + transposes (+ XOR-swizzled w3 LDS image)
// ---------------------------------------------------------------------------
__global__ void k_prep(const float* __restrict__ w1a, const float* __restrict__ w3,
                       const float* __restrict__ w1b, u16* __restrict__ w1at,
                       u16* __restrict__ w3img, u16* __restrict__ w1bt)
{
    int i = blockIdx.x * 256 + threadIdx.x;
    if (i < 16384) {
        int k = i >> 6, d = i & 63;
        w1at[d * 256 + k] = (u16)f2bf(w1a[i]);
    } else if (i < 126976) {
        int j = i - 16384;
        int k = j >> 12, c = (j >> 6) & 63, d = j & 63;
        w3img[(size_t)k * 4096 + d * 64 + (c ^ ((d & 7) << 3))] = (u16)f2bf(w3[j]);
    } else if (i < 143360) {
        int j = i - 126976;
        int c = j >> 8, d = j & 255;
        w1bt[d * 64 + c] = (u16)f2bf(w1b[j]);
    }
}

// ---------------------------------------------------------------------------
// GEMM1: t1[N,64](bf16) = data[N,256](f32->bf16) @ w1a ; GN1 stats
// ---------------------------------------------------------------------------
__global__ __launch_bounds__(256) void k_gemm1(const float* __restrict__ data,
        const u16* __restrict__ w1at, u16* __restrict__ t1,
        float* __restrict__ stats, int n)
{
    __shared__ float s_sum[32], s_sq[32];
    const int tid = threadIdx.x;
    if (tid < 32) { s_sum[tid] = 0.f; s_sq[tid] = 0.f; }
    __syncthreads();
    const int l = tid & 63, wv = tid >> 6;
    const int ll = l & 15, lh = l >> 4;
    const int rowbase = blockIdx.x * 256 + wv * 64;

    f32x4 acc[4][4] = {};
#pragma unroll
    for (int kc = 0; kc < 8; ++kc) {
        short8 b[4];
#pragma unroll
        for (int f = 0; f < 4; ++f)
            b[f] = *(const short8*)(w1at + (size_t)(f * 16 + ll) * 256 + kc * 32 + lh * 8);
#pragma unroll
        for (int rt = 0; rt < 4; ++rt) {
            int row = rowbase + rt * 16 + ll;
            int rowc = (row < n) ? row : 0;
            const float* ar = data + (size_t)rowc * CIN + kc * 32 + lh * 8;
            short8 a = pack8(*(const float4*)ar, *(const float4*)(ar + 4));
#pragma unroll
            for (int f = 0; f < 4; ++f)
                acc[rt][f] = __builtin_amdgcn_mfma_f32_16x16x32_bf16(a, b[f], acc[rt][f], 0, 0, 0);
        }
    }
    float gs[4] = {0.f, 0.f, 0.f, 0.f}, gq[4] = {0.f, 0.f, 0.f, 0.f};
#pragma unroll
    for (int rt = 0; rt < 4; ++rt) {
#pragma unroll
        for (int f = 0; f < 4; ++f) {
#pragma unroll
            for (int r = 0; r < 4; ++r) {
                int rr = rowbase + rt * 16 + lh * 4 + r;
                if (rr < n) {
                    float v = acc[rt][f][r];
                    t1[(size_t)rr * CB + f * 16 + ll] = (u16)f2bf(v);
                    gs[f] += v; gq[f] += v * v;
                }
            }
        }
    }
#pragma unroll
    for (int f = 0; f < 4; ++f) {
        float s = gs[f], q = gq[f];
        s += __shfl_xor(s, 1); s += __shfl_xor(s, 16); s += __shfl_xor(s, 32);
        q += __shfl_xor(q, 1); q += __shfl_xor(q, 16); q += __shfl_xor(q, 32);
        if ((l & 0x31) == 0) {
            atomicAdd(&s_sum[f * 8 + (ll >> 1)], s);
            atomicAdd(&s_sq [f * 8 + (ll >> 1)], q);
        }
    }
    __syncthreads();
    if (tid < 32) {
        atomicAdd(&stats[tid], s_sum[tid]);
        atomicAdd(&stats[32 + tid], s_sq[tid]);
    }
}

// ---------------------------------------------------------------------------
// GN apply + ReLU, in-place on a [N,64] bf16 buffer (2 channels per group)
// ---------------------------------------------------------------------------
__global__ void k_apply64(u16* __restrict__ buf, const float* __restrict__ st,
        const float* __restrict__ gamma, const float* __restrict__ beta, int n)
{
    const float cnt = (float)n * 2.0f;
    const int total = n * 8;
    for (int i = blockIdx.x * blockDim.x + threadIdx.x; i < total;
         i += gridDim.x * blockDim.x) {
        int c0 = (i & 7) * 8;
        short8 v = ((short8*)buf)[i];
#pragma unroll
        for (int j = 0; j < 8; ++j) {
            int c = c0 + j, g = c >> 1;
            float mu = st[g] / cnt;
            float var = st[32 + g] / cnt - mu * mu;
            float inv = rsqrtf(var + EPS);
            float x = bf2f(v[j]);
            x = fmaxf((x - mu) * inv * gamma[c] + beta[c], 0.f);
            v[j] = f2bf(x);
        }
        ((short8*)buf)[i] = v;
    }
}

// ---------------------------------------------------------------------------
// Octree conv (bf16 MFMA): y[n,d] = sum_k sum_c x[neigh[n,k],c] * w3[k,c,d]
// 128 nodes x 64 d per block, 4 waves (each: 32 nodes x 64 d, acc[2][4]).
// Per k: issue w3[k+1] loads -> issue k+1 gathers -> ds_read B + 16 MFMA
// (B frags reused across both row tiles) -> ds_write staged w3 -> barrier.
// ---------------------------------------------------------------------------
__global__ __launch_bounds__(256, 4) void k_conv(const u16* __restrict__ xb,
        const int* __restrict__ neigh, const u16* __restrict__ w3img,
        u16* __restrict__ y, float* __restrict__ stats, int n)
{
    __shared__ u16 s_w3[2][4096];     // 2 x 8 KB swizzled [64d][64c] images
    __shared__ int s_idx[128 * KNB];
    __shared__ float s_sum[32], s_sq[32];
    const int tid = threadIdx.x;
    if (tid < 32) { s_sum[tid] = 0.f; s_sq[tid] = 0.f; }
    const int row0 = blockIdx.x * 128;
    for (int j = tid; j < 128 * KNB; j += 256) {
        int node = row0 + j / KNB;
        s_idx[j] = (node < n) ? neigh[(size_t)row0 * KNB + j] : 0;
    }
    const int l = tid & 63, wv = tid >> 6;
    const int ll = l & 15, lh = l >> 4;

    // prologue: stage w3[0] into buffer 0
    {
        const short8* src = (const short8*)(w3img);
        short8 v0 = src[tid * 2], v1 = src[tid * 2 + 1];
        ((short8*)&s_w3[0][0])[tid * 2] = v0;
        ((short8*)&s_w3[0][0])[tid * 2 + 1] = v1;
    }
    __syncthreads();
    short8 a0c[2], a1c[2];
#pragma unroll
    for (int rt = 0; rt < 2; ++rt) {
        int idx = s_idx[(wv * 32 + rt * 16 + ll) * KNB];
        const u16* xr = xb + (size_t)idx * CB + lh * 8;
        a0c[rt] = *(const short8*)(xr);
        a1c[rt] = *(const short8*)(xr + 32);
    }

    f32x4 acc[2][4] = {};
    for (int k = 0; k < KNB; ++k) {
        const int cur = k & 1;
        const bool more = (k + 1 < KNB);
        short8 w0, w1;
        short8 a0n[2], a1n[2];
        if (more) {
            // issue-early: w3[k+1] global loads (written to LDS after MFMA)
            const short8* src = (const short8*)(w3img + (size_t)(k + 1) * 4096);
            w0 = src[tid * 2];
            w1 = src[tid * 2 + 1];
            // issue gathers for k+1
#pragma unroll
            for (int rt = 0; rt < 2; ++rt) {
                int idx = s_idx[(wv * 32 + rt * 16 + ll) * KNB + k + 1];
                const u16* xr = xb + (size_t)idx * CB + lh * 8;
                a0n[rt] = *(const short8*)(xr);
                a1n[rt] = *(const short8*)(xr + 32);
            }
        }
        // compute tile k: B frags read once, reused across both row tiles
#pragma unroll
        for (int f = 0; f < 4; ++f) {
            int d = f * 16 + ll;
            int swz = (d & 7) << 4;
            short8 b0 = *(const short8*)((const char*)&s_w3[cur][0] + d * 128 + ((lh * 16) ^ swz));
            short8 b1 = *(const short8*)((const char*)&s_w3[cur][0] + d * 128 + ((64 + lh * 16) ^ swz));
#pragma unroll
            for (int rt = 0; rt < 2; ++rt) {
                acc[rt][f] = __builtin_amdgcn_mfma_f32_16x16x32_bf16(a0c[rt], b0, acc[rt][f], 0, 0, 0);
                acc[rt][f] = __builtin_amdgcn_mfma_f32_16x16x32_bf16(a1c[rt], b1, acc[rt][f], 0, 0, 0);
            }
        }
        if (more) {
            // write-late: staged w3 regs -> other LDS buffer
            ((short8*)&s_w3[cur ^ 1][0])[tid * 2] = w0;
            ((short8*)&s_w3[cur ^ 1][0])[tid * 2 + 1] = w1;
#pragma unroll
            for (int rt = 0; rt < 2; ++rt) { a0c[rt] = a0n[rt]; a1c[rt] = a1n[rt]; }
        }
        __syncthreads();
    }
    float gs[4] = {0.f, 0.f, 0.f, 0.f}, gq[4] = {0.f, 0.f, 0.f, 0.f};
#pragma unroll
    for (int rt = 0; rt < 2; ++rt) {
#pragma unroll
        for (int f = 0; f < 4; ++f) {
#pragma unroll
            for (int r = 0; r < 4; ++r) {
                int rr = row0 + wv * 32 + rt * 16 + lh * 4 + r;
                if (rr < n) {
                    float v = acc[rt][f][r];
                    y[(size_t)rr * CB + f * 16 + ll] = (u16)f2bf(v);
                    gs[f] += v; gq[f] += v * v;
                }
            }
        }
    }
#pragma unroll
    for (int f = 0; f < 4; ++f) {
        float s = gs[f], q = gq[f];
        s += __shfl_xor(s, 1); s += __shfl_xor(s, 16); s += __shfl_xor(s, 32);
        q += __shfl_xor(q, 1); q += __shfl_xor(q, 16); q += __shfl_xor(q, 32);
        if ((l & 0x31) == 0) {
            atomicAdd(&s_sum[f * 8 + (ll >> 1)], s);
            atomicAdd(&s_sq [f * 8 + (ll >> 1)], q);
        }
    }
    __syncthreads();
    if (tid < 32) {
        atomicAdd(&stats[64 + tid], s_sum[tid]);
        atomicAdd(&stats[96 + tid], s_sq[tid]);
    }
}

// ---------------------------------------------------------------------------
// GEMM2: z[N,256] = y2[N,64](bf16) @ w1b ; GN3 stats.
// Stores bf16 into zb (if non-null) else f32 into z.
// ---------------------------------------------------------------------------
__global__ __launch_bounds__(256) void k_gemm2(const u16* __restrict__ y2,
        const u16* __restrict__ w1bt, float* __restrict__ z, u16* __restrict__ zb,
        float* __restrict__ stats, int n)
{
    __shared__ float s_sum[8], s_sq[8];
    const int tid = threadIdx.x;
    if (tid < 8) { s_sum[tid] = 0.f; s_sq[tid] = 0.f; }
    __syncthreads();
    const int l = tid & 63, wv = tid >> 6;
    const int ll = l & 15, lh = l >> 4;
    const int rowbase = blockIdx.x * 256 + wv * 64;
    const int cb = blockIdx.y;

    short8 b0[4], b1[4];
#pragma unroll
    for (int f = 0; f < 4; ++f) {
        const u16* br = w1bt + (size_t)(cb * 64 + f * 16 + ll) * CB + lh * 8;
        b0[f] = *(const short8*)(br);
        b1[f] = *(const short8*)(br + 32);
    }
    f32x4 acc[4][4] = {};
#pragma unroll
    for (int rt = 0; rt < 4; ++rt) {
        int row = rowbase + rt * 16 + ll;
        int rowc = (row < n) ? row : 0;
        const u16* ar = y2 + (size_t)rowc * CB + lh * 8;
        short8 a0 = *(const short8*)(ar);
        short8 a1 = *(const short8*)(ar + 32);
#pragma unroll
        for (int f = 0; f < 4; ++f) {
            acc[rt][f] = __builtin_amdgcn_mfma_f32_16x16x32_bf16(a0, b0[f], acc[rt][f], 0, 0, 0);
            acc[rt][f] = __builtin_amdgcn_mfma_f32_16x16x32_bf16(a1, b1[f], acc[rt][f], 0, 0, 0);
        }
    }
    float gs[4] = {0.f, 0.f, 0.f, 0.f}, gq[4] = {0.f, 0.f, 0.f, 0.f};
#pragma unroll
    for (int rt = 0; rt < 4; ++rt) {
#pragma unroll
        for (int f = 0; f < 4; ++f) {
#pragma unroll
            for (int r = 0; r < 4; ++r) {
                int rr = rowbase + rt * 16 + lh * 4 + r;
                if (rr < n) {
                    float v = acc[rt][f][r];
                    size_t off = (size_t)rr * COUT + cb * 64 + f * 16 + ll;
                    if (zb) zb[off] = (u16)f2bf(v); else z[off] = v;
                    gs[f] += v; gq[f] += v * v;
                }
            }
        }
    }
#pragma unroll
    for (int f = 0; f < 4; ++f) {
        float s = gs[f], q = gq[f];
        s += __shfl_xor(s, 1); s += __shfl_xor(s, 2); s += __shfl_xor(s, 4);
        s += __shfl_xor(s, 16); s += __shfl_xor(s, 32);
        q += __shfl_xor(q, 1); q += __shfl_xor(q, 2); q += __shfl_xor(q, 4);
        q += __shfl_xor(q, 16); q += __shfl_xor(q, 32);
        if ((l & 0x37) == 0) {
            atomicAdd(&s_sum[f * 2 + (ll >> 3)], s);
            atomicAdd(&s_sq [f * 2 + (ll >> 3)], q);
        }
    }
    __syncthreads();
    if (tid < 8) {
        atomicAdd(&stats[128 + cb * 8 + tid], s_sum[tid]);
        atomicAdd(&stats[160 + cb * 8 + tid], s_sq[tid]);
    }
}

// ---------------------------------------------------------------------------
// Final: out = relu(GN3(z) + data). bf16-z variant (z in ws).
// ---------------------------------------------------------------------------
__global__ void k_final_bf(float* __restrict__ out, const u16* __restrict__ zb,
        const float* __restrict__ data, const float* __restrict__ st,
        const float* __restrict__ gamma, const float* __restrict__ beta, int n)
{
    const float cnt = (float)n * 8.0f;
    const int total = n * 32;   // 8-channel chunks
    for (int i = blockIdx.x * blockDim.x + threadIdx.x; i < total;
         i += gridDim.x * blockDim.x) {
        int c0 = (i & 31) * 8;
        int g = c0 >> 3;
        float mu = st[g] / cnt;
        float var = st[32 + g] / cnt - mu * mu;
        float inv = rsqrtf(var + EPS);
        short8 zv = ((const short8*)zb)[i];
        float dd[8], oo[8];
        *(float4*)dd = *(const float4*)(data + (size_t)i * 8);
        *(float4*)(dd + 4) = *(const float4*)(data + (size_t)i * 8 + 4);
#pragma unroll
        for (int j = 0; j < 8; ++j)
            oo[j] = fmaxf((bf2f(zv[j]) - mu) * inv * gamma[c0 + j] + beta[c0 + j] + dd[j], 0.f);
        *(float4*)(out + (size_t)i * 8) = *(float4*)oo;
        *(float4*)(out + (size_t)i * 8 + 4) = *(float4*)(oo + 4);
    }
}

// f32-z fallback (z already in d_out), in-place
__global__ void k_final(float* __restrict__ zo, const float* __restrict__ data,
        const float* __restrict__ st, const float* __restrict__ gamma,
        const float* __restrict__ beta, int n)
{
    const float cnt = (float)n * 8.0f;
    const int total = n * (COUT / 4);
    for (int i = blockIdx.x * blockDim.x + threadIdx.x; i < total;
         i += gridDim.x * blockDim.x) {
        int c4 = (i & (COUT / 4 - 1)) * 4;
        int g = c4 >> 3;
        float mu = st[g] / cnt;
        float var = st[32 + g] / cnt - mu * mu;
        float inv = rsqrtf(var + EPS);
        float4 zv = *(float4*)(zo + (size_t)i * 4);
        float4 dv = *(const float4*)(data + (size_t)i * 4);
        zv.x = fmaxf((zv.x - mu) * inv * gamma[c4 + 0] + beta[c4 + 0] + dv.x, 0.f);
        zv.y = fmaxf((zv.y - mu) * inv * gamma[c4 + 1] + beta[c4 + 1] + dv.y, 0.f);
        zv.z = fmaxf((zv.z - mu) * inv * gamma[c4 + 2] + beta[c4 + 2] + dv.z, 0.f);
        zv.w = fmaxf((zv.w - mu) * inv * gamma[c4 + 3] + beta[c4 + 3] + dv.w, 0.f);
        *(float4*)(zo + (size_t)i * 4) = zv;
    }
}

// ---------------------------------------------------------------------------
extern "C" void kernel_launch(void* const* d_in, const int* in_sizes, int n_in,
                              void* d_out, int out_size, void* d_ws, size_t ws_size,
                              hipStream_t stream)
{
    const float* data = (const float*)d_in[0];
    const int*   neigh = (const int*)d_in[1];
    const float* w1a = (const float*)d_in[2];
    const float* g1a = (const float*)d_in[3];
    const float* b1a = (const float*)d_in[4];
    const float* w3  = (const float*)d_in[5];
    const float* g3  = (const float*)d_in[6];
    const float* b3  = (const float*)d_in[7];
    const float* w1b = (const float*)d_in[8];
    const float* g1b = (const float*)d_in[9];
    const float* b1b = (const float*)d_in[10];
    float* out = (float*)d_out;
    float* ws  = (float*)d_ws;

    const int n = in_sizes[0] / CIN;   // 150000

    // ws layout: stats[192] (pad 256 f32) | w1at | w3img | w1bt | t1 | ybuf | [zb]
    float* stats = ws;
    u16* w1at  = (u16*)(ws + 256);
    u16* w3img = w1at + 16384;
    u16* w1bt  = w3img + 110592;
    u16* t1    = w1bt + 16384;
    u16* ybuf  = t1 + (size_t)n * CB;
    u16* zb    = nullptr;
    {
        size_t need = 1024 + 286720 + (size_t)n * CB * 4 + (size_t)n * COUT * 2;
        if (ws_size >= need) zb = ybuf + (size_t)n * CB;
    }

    hipMemsetAsync(stats, 0, 192 * sizeof(float), stream);

    const int nb128 = (n + 127) / 128;
    const int nb256 = (n + 255) / 256;
    k_prep<<<560, 256, 0, stream>>>(w1a, w3, w1b, w1at, w3img, w1bt);
    k_gemm1<<<nb256, 256, 0, stream>>>(data, w1at, t1, stats, n);
    k_apply64<<<2048, 256, 0, stream>>>(t1, stats, g1a, b1a, n);
    k_conv<<<nb128, 256, 0, stream>>>(t1, neigh, w3img, ybuf, stats, n);
    k_apply64<<<2048, 256, 0, stream>>>(ybuf, stats + 64, g3, b3, n);
    k_gemm2<<<dim3(nb256, 4), 256, 0, stream>>>(ybuf, w1bt, out, zb, stats, n);
    if (zb)
        k_final_bf<<<2048, 256, 0, stream>>>(out, zb, data, stats + 128, g1b, b1b, n);
    else
        k_final<<<2048, 256, 0, stream>>>(out, data, stats + 128, g1b, b1b, n);
}

// Round 5
// 296.120 us; speedup vs baseline: 2.9403x; 1.0009x over previous
//
#include <hip/hip_runtime.h>
#include <math.h>

#define CIN 256
#define CB 64
#define COUT 256
#define KNB 27
#define EPS 1e-5f

typedef unsigned short u16;
typedef __attribute__((ext_vector_type(8))) short short8;
typedef __attribute__((ext_vector_type(4))) float f32x4;

__device__ inline short f2bf(float f) {
    union { float f; unsigned u; } v; v.f = f;
    unsigned r = v.u + 0x7fff + ((v.u >> 16) & 1);   // RNE
    return (short)(r >> 16);
}
__device__ inline float bf2f(short s) {
    union { unsigned u; float f; } v; v.u = ((unsigned)(u16)s) << 16;
    return v.f;
}
__device__ inline short8 pack8(float4 x0, float4 x1) {
    short8 r;
    r[0] = f2bf(x0.x); r[1] = f2bf(x0.y); r[2] = f2bf(x0.z); r[3] = f2bf(x0.w);
    r[4] = f2bf(x1.x); r[5] = f2bf(x1.y); r[6] = f2bf(x1.z); r[7] = f2bf(x1.w);
    return r;
}

// ---------------------------------------------------------------------------
// Weight prep: bf16 conversion + transposes (+ XOR-swizzled w3 LDS image)
// ---------------------------------------------------------------------------
__global__ void k_prep(const float* __restrict__ w1a, const float* __restrict__ w3,
                       const float* __restrict__ w1b, u16* __restrict__ w1at,
                       u16* __restrict__ w3img, u16* __restrict__ w1bt)
{
    int i = blockIdx.x * 256 + threadIdx.x;
    if (i < 16384) {
        int k = i >> 6, d = i & 63;
        w1at[d * 256 + k] = (u16)f2bf(w1a[i]);
    } else if (i < 126976) {
        int j = i - 16384;
        int k = j >> 12, c = (j >> 6) & 63, d = j & 63;
        w3img[(size_t)k * 4096 + d * 64 + (c ^ ((d & 7) << 3))] = (u16)f2bf(w3[j]);
    } else if (i < 143360) {
        int j = i - 126976;
        int c = j >> 8, d = j & 255;
        w1bt[d * 64 + c] = (u16)f2bf(w1b[j]);
    }
}

// ---------------------------------------------------------------------------
// GEMM1: t1[N,64](bf16) = data[N,256](f32->bf16) @ w1a ; GN1 stats
// ---------------------------------------------------------------------------
__global__ __launch_bounds__(256) void k_gemm1(const float* __restrict__ data,
        const u16* __restrict__ w1at, u16* __restrict__ t1,
        float* __restrict__ stats, int n)
{
    __shared__ float s_sum[32], s_sq[32];
    const int tid = threadIdx.x;
    if (tid < 32) { s_sum[tid] = 0.f; s_sq[tid] = 0.f; }
    __syncthreads();
    const int l = tid & 63, wv = tid >> 6;
    const int ll = l & 15, lh = l >> 4;
    const int rowbase = blockIdx.x * 256 + wv * 64;

    f32x4 acc[4][4] = {};
#pragma unroll
    for (int kc = 0; kc < 8; ++kc) {
        short8 b[4];
#pragma unroll
        for (int f = 0; f < 4; ++f)
            b[f] = *(const short8*)(w1at + (size_t)(f * 16 + ll) * 256 + kc * 32 + lh * 8);
#pragma unroll
        for (int rt = 0; rt < 4; ++rt) {
            int row = rowbase + rt * 16 + ll;
            int rowc = (row < n) ? row : 0;
            const float* ar = data + (size_t)rowc * CIN + kc * 32 + lh * 8;
            short8 a = pack8(*(const float4*)ar, *(const float4*)(ar + 4));
#pragma unroll
            for (int f = 0; f < 4; ++f)
                acc[rt][f] = __builtin_amdgcn_mfma_f32_16x16x32_bf16(a, b[f], acc[rt][f], 0, 0, 0);
        }
    }
    float gs[4] = {0.f, 0.f, 0.f, 0.f}, gq[4] = {0.f, 0.f, 0.f, 0.f};
#pragma unroll
    for (int rt = 0; rt < 4; ++rt) {
#pragma unroll
        for (int f = 0; f < 4; ++f) {
#pragma unroll
            for (int r = 0; r < 4; ++r) {
                int rr = rowbase + rt * 16 + lh * 4 + r;
                if (rr < n) {
                    float v = acc[rt][f][r];
                    t1[(size_t)rr * CB + f * 16 + ll] = (u16)f2bf(v);
                    gs[f] += v; gq[f] += v * v;
                }
            }
        }
    }
#pragma unroll
    for (int f = 0; f < 4; ++f) {
        float s = gs[f], q = gq[f];
        s += __shfl_xor(s, 1); s += __shfl_xor(s, 16); s += __shfl_xor(s, 32);
        q += __shfl_xor(q, 1); q += __shfl_xor(q, 16); q += __shfl_xor(q, 32);
        if ((l & 0x31) == 0) {
            atomicAdd(&s_sum[f * 8 + (ll >> 1)], s);
            atomicAdd(&s_sq [f * 8 + (ll >> 1)], q);
        }
    }
    __syncthreads();
    if (tid < 32) {
        atomicAdd(&stats[tid], s_sum[tid]);
        atomicAdd(&stats[32 + tid], s_sq[tid]);
    }
}

// ---------------------------------------------------------------------------
// GN apply + ReLU, in-place on a [N,64] bf16 buffer (2 channels per group)
// ---------------------------------------------------------------------------
__global__ void k_apply64(u16* __restrict__ buf, const float* __restrict__ st,
        const float* __restrict__ gamma, const float* __restrict__ beta, int n)
{
    const float cnt = (float)n * 2.0f;
    const int total = n * 8;
    for (int i = blockIdx.x * blockDim.x + threadIdx.x; i < total;
         i += gridDim.x * blockDim.x) {
        int c0 = (i & 7) * 8;
        short8 v = ((short8*)buf)[i];
#pragma unroll
        for (int j = 0; j < 8; ++j) {
            int c = c0 + j, g = c >> 1;
            float mu = st[g] / cnt;
            float var = st[32 + g] / cnt - mu * mu;
            float inv = rsqrtf(var + EPS);
            float x = bf2f(v[j]);
            x = fmaxf((x - mu) * inv * gamma[c] + beta[c], 0.f);
            v[j] = f2bf(x);
        }
        ((short8*)buf)[i] = v;
    }
}

// ---------------------------------------------------------------------------
// Octree conv (bf16 MFMA): y[n,d] = sum_k sum_c x[neigh[n,k],c] * w3[k,c,d]
// 64 nodes x 64 d per block, 4 waves (each 16 rows). No s_idx: per-lane
// direct neigh loads with 2-step prefetch; gathers prefetched 1 step;
// dbuf w3 LDS (issue-early / write-late). LDS 16.6 KB -> high occupancy.
// ---------------------------------------------------------------------------
__global__ __launch_bounds__(256) void k_conv(const u16* __restrict__ xb,
        const int* __restrict__ neigh, const u16* __restrict__ w3img,
        u16* __restrict__ y, float* __restrict__ stats, int n)
{
    __shared__ u16 s_w3[2][4096];     // 2 x 8 KB swizzled [64d][64c] images
    __shared__ float s_sum[32], s_sq[32];
    const int tid = threadIdx.x;
    if (tid < 32) { s_sum[tid] = 0.f; s_sq[tid] = 0.f; }
    const int row0 = blockIdx.x * 64;
    const int l = tid & 63, wv = tid >> 6;
    const int ll = l & 15, lh = l >> 4;
    const int myrow = row0 + wv * 16 + ll;
    const int rowc = (myrow < n) ? myrow : 0;
    const int* __restrict__ nrow = neigh + (size_t)rowc * KNB;

    // prologue: stage w3[0] into buffer 0; load idx 0,1
    {
        const short8* src = (const short8*)(w3img);
        short8 v0 = src[tid * 2], v1 = src[tid * 2 + 1];
        ((short8*)&s_w3[0][0])[tid * 2] = v0;
        ((short8*)&s_w3[0][0])[tid * 2 + 1] = v1;
    }
    int idx0 = nrow[0];
    int idxn = nrow[1];
    __syncthreads();
    short8 a0c, a1c;
    {
        const u16* xr = xb + (size_t)idx0 * CB + lh * 8;
        a0c = *(const short8*)(xr);
        a1c = *(const short8*)(xr + 32);
    }

    f32x4 acc[4] = {};
    for (int k = 0; k < KNB; ++k) {
        const int cur = k & 1;
        const bool more = (k + 1 < KNB);
        int idx2 = 0;
        short8 w0, w1, a0n, a1n;
        if (k + 2 < KNB) idx2 = nrow[k + 2];        // idx prefetch (2 ahead)
        if (more) {
            // issue-early: w3[k+1] global loads (LDS write deferred)
            const short8* src = (const short8*)(w3img + (size_t)(k + 1) * 4096);
            w0 = src[tid * 2];
            w1 = src[tid * 2 + 1];
            // gather prefetch (1 ahead)
            const u16* xr = xb + (size_t)idxn * CB + lh * 8;
            a0n = *(const short8*)(xr);
            a1n = *(const short8*)(xr + 32);
        }
        // compute tile k
#pragma unroll
        for (int f = 0; f < 4; ++f) {
            int d = f * 16 + ll;
            int swz = (d & 7) << 4;
            short8 b0 = *(const short8*)((const char*)&s_w3[cur][0] + d * 128 + ((lh * 16) ^ swz));
            short8 b1 = *(const short8*)((const char*)&s_w3[cur][0] + d * 128 + ((64 + lh * 16) ^ swz));
            acc[f] = __builtin_amdgcn_mfma_f32_16x16x32_bf16(a0c, b0, acc[f], 0, 0, 0);
            acc[f] = __builtin_amdgcn_mfma_f32_16x16x32_bf16(a1c, b1, acc[f], 0, 0, 0);
        }
        if (more) {
            // write-late: staged w3 regs -> other LDS buffer
            ((short8*)&s_w3[cur ^ 1][0])[tid * 2] = w0;
            ((short8*)&s_w3[cur ^ 1][0])[tid * 2 + 1] = w1;
            a0c = a0n; a1c = a1n; idxn = idx2;
        }
        __syncthreads();
    }
    float gs[4] = {0.f, 0.f, 0.f, 0.f}, gq[4] = {0.f, 0.f, 0.f, 0.f};
#pragma unroll
    for (int f = 0; f < 4; ++f) {
#pragma unroll
        for (int r = 0; r < 4; ++r) {
            int rr = row0 + wv * 16 + lh * 4 + r;
            if (rr < n) {
                float v = acc[f][r];
                y[(size_t)rr * CB + f * 16 + ll] = (u16)f2bf(v);
                gs[f] += v; gq[f] += v * v;
            }
        }
    }
#pragma unroll
    for (int f = 0; f < 4; ++f) {
        float s = gs[f], q = gq[f];
        s += __shfl_xor(s, 1); s += __shfl_xor(s, 16); s += __shfl_xor(s, 32);
        q += __shfl_xor(q, 1); q += __shfl_xor(q, 16); q += __shfl_xor(q, 32);
        if ((l & 0x31) == 0) {
            atomicAdd(&s_sum[f * 8 + (ll >> 1)], s);
            atomicAdd(&s_sq [f * 8 + (ll >> 1)], q);
        }
    }
    __syncthreads();
    if (tid < 32) {
        atomicAdd(&stats[64 + tid], s_sum[tid]);
        atomicAdd(&stats[96 + tid], s_sq[tid]);
    }
}

// ---------------------------------------------------------------------------
// GEMM2 with fused GN2-apply on the A path:
// z[N,256] = relu(gn2(y))[N,64](bf16) @ w1b ; GN3 stats.
// y is read RAW (pre-GN); per-lane scale/shift regs apply GN2+ReLU.
// Stores bf16 into zb (if non-null) else f32 into z.
// ---------------------------------------------------------------------------
__global__ __launch_bounds__(256) void k_gemm2(const u16* __restrict__ y2,
        const u16* __restrict__ w1bt, float* __restrict__ z, u16* __restrict__ zb,
        float* __restrict__ stats, const float* __restrict__ g3,
        const float* __restrict__ b3, int n)
{
    __shared__ float s_sum[8], s_sq[8];
    const int tid = threadIdx.x;
    if (tid < 8) { s_sum[tid] = 0.f; s_sq[tid] = 0.f; }
    __syncthreads();
    const int l = tid & 63, wv = tid >> 6;
    const int ll = l & 15, lh = l >> 4;
    const int rowbase = blockIdx.x * 256 + wv * 64;
    const int cb = blockIdx.y;

    // per-lane GN2 scale/shift for the 16 k-channels this lane touches
    const float* st2 = stats + 64;
    const float cnt2 = (float)n * 2.0f;
    float sc[16], sh[16];
#pragma unroll
    for (int j = 0; j < 16; ++j) {
        int c = (j < 8) ? (lh * 8 + j) : (32 + lh * 8 + (j - 8));
        int g = c >> 1;
        float mu = st2[g] / cnt2;
        float var = st2[32 + g] / cnt2 - mu * mu;
        float inv = rsqrtf(var + EPS);
        float gm = g3[c];
        sc[j] = inv * gm;
        sh[j] = b3[c] - mu * inv * gm;
    }

    short8 b0[4], b1[4];
#pragma unroll
    for (int f = 0; f < 4; ++f) {
        const u16* br = w1bt + (size_t)(cb * 64 + f * 16 + ll) * CB + lh * 8;
        b0[f] = *(const short8*)(br);
        b1[f] = *(const short8*)(br + 32);
    }
    f32x4 acc[4][4] = {};
#pragma unroll
    for (int rt = 0; rt < 4; ++rt) {
        int row = rowbase + rt * 16 + ll;
        int rowc = (row < n) ? row : 0;
        const u16* ar = y2 + (size_t)rowc * CB + lh * 8;
        short8 r0 = *(const short8*)(ar);
        short8 r1 = *(const short8*)(ar + 32);
        short8 a0, a1;
#pragma unroll
        for (int j = 0; j < 8; ++j) {
            a0[j] = f2bf(fmaxf(bf2f(r0[j]) * sc[j] + sh[j], 0.f));
            a1[j] = f2bf(fmaxf(bf2f(r1[j]) * sc[8 + j] + sh[8 + j], 0.f));
        }
#pragma unroll
        for (int f = 0; f < 4; ++f) {
            acc[rt][f] = __builtin_amdgcn_mfma_f32_16x16x32_bf16(a0, b0[f], acc[rt][f], 0, 0, 0);
            acc[rt][f] = __builtin_amdgcn_mfma_f32_16x16x32_bf16(a1, b1[f], acc[rt][f], 0, 0, 0);
        }
    }
    float gs[4] = {0.f, 0.f, 0.f, 0.f}, gq[4] = {0.f, 0.f, 0.f, 0.f};
#pragma unroll
    for (int rt = 0; rt < 4; ++rt) {
#pragma unroll
        for (int f = 0; f < 4; ++f) {
#pragma unroll
            for (int r = 0; r < 4; ++r) {
                int rr = rowbase + rt * 16 + lh * 4 + r;
                if (rr < n) {
                    float v = acc[rt][f][r];
                    size_t off = (size_t)rr * COUT + cb * 64 + f * 16 + ll;
                    if (zb) zb[off] = (u16)f2bf(v); else z[off] = v;
                    gs[f] += v; gq[f] += v * v;
                }
            }
        }
    }
#pragma unroll
    for (int f = 0; f < 4; ++f) {
        float s = gs[f], q = gq[f];
        s += __shfl_xor(s, 1); s += __shfl_xor(s, 2); s += __shfl_xor(s, 4);
        s += __shfl_xor(s, 16); s += __shfl_xor(s, 32);
        q += __shfl_xor(q, 1); q += __shfl_xor(q, 2); q += __shfl_xor(q, 4);
        q += __shfl_xor(q, 16); q += __shfl_xor(q, 32);
        if ((l & 0x37) == 0) {
            atomicAdd(&s_sum[f * 2 + (ll >> 3)], s);
            atomicAdd(&s_sq [f * 2 + (ll >> 3)], q);
        }
    }
    __syncthreads();
    if (tid < 8) {
        atomicAdd(&stats[128 + cb * 8 + tid], s_sum[tid]);
        atomicAdd(&stats[160 + cb * 8 + tid], s_sq[tid]);
    }
}

// ---------------------------------------------------------------------------
// Final: out = relu(GN3(z) + data). bf16-z variant (z in ws).
// ---------------------------------------------------------------------------
__global__ void k_final_bf(float* __restrict__ out, const u16* __restrict__ zb,
        const float* __restrict__ data, const float* __restrict__ st,
        const float* __restrict__ gamma, const float* __restrict__ beta, int n)
{
    const float cnt = (float)n * 8.0f;
    const int total = n * 32;   // 8-channel chunks
    for (int i = blockIdx.x * blockDim.x + threadIdx.x; i < total;
         i += gridDim.x * blockDim.x) {
        int c0 = (i & 31) * 8;
        int g = c0 >> 3;
        float mu = st[g] / cnt;
        float var = st[32 + g] / cnt - mu * mu;
        float inv = rsqrtf(var + EPS);
        short8 zv = ((const short8*)zb)[i];
        float dd[8], oo[8];
        *(float4*)dd = *(const float4*)(data + (size_t)i * 8);
        *(float4*)(dd + 4) = *(const float4*)(data + (size_t)i * 8 + 4);
#pragma unroll
        for (int j = 0; j < 8; ++j)
            oo[j] = fmaxf((bf2f(zv[j]) - mu) * inv * gamma[c0 + j] + beta[c0 + j] + dd[j], 0.f);
        *(float4*)(out + (size_t)i * 8) = *(float4*)oo;
        *(float4*)(out + (size_t)i * 8 + 4) = *(float4*)(oo + 4);
    }
}

// f32-z fallback (z already in d_out), in-place
__global__ void k_final(float* __restrict__ zo, const float* __restrict__ data,
        const float* __restrict__ st, const float* __restrict__ gamma,
        const float* __restrict__ beta, int n)
{
    const float cnt = (float)n * 8.0f;
    const int total = n * (COUT / 4);
    for (int i = blockIdx.x * blockDim.x + threadIdx.x; i < total;
         i += gridDim.x * blockDim.x) {
        int c4 = (i & (COUT / 4 - 1)) * 4;
        int g = c4 >> 3;
        float mu = st[g] / cnt;
        float var = st[32 + g] / cnt - mu * mu;
        float inv = rsqrtf(var + EPS);
        float4 zv = *(float4*)(zo + (size_t)i * 4);
        float4 dv = *(const float4*)(data + (size_t)i * 4);
        zv.x = fmaxf((zv.x - mu) * inv * gamma[c4 + 0] + beta[c4 + 0] + dv.x, 0.f);
        zv.y = fmaxf((zv.y - mu) * inv * gamma[c4 + 1] + beta[c4 + 1] + dv.y, 0.f);
        zv.z = fmaxf((zv.z - mu) * inv * gamma[c4 + 2] + beta[c4 + 2] + dv.z, 0.f);
        zv.w = fmaxf((zv.w - mu) * inv * gamma[c4 + 3] + beta[c4 + 3] + dv.w, 0.f);
        *(float4*)(zo + (size_t)i * 4) = zv;
    }
}

// ---------------------------------------------------------------------------
extern "C" void kernel_launch(void* const* d_in, const int* in_sizes, int n_in,
                              void* d_out, int out_size, void* d_ws, size_t ws_size,
                              hipStream_t stream)
{
    const float* data = (const float*)d_in[0];
    const int*   neigh = (const int*)d_in[1];
    const float* w1a = (const float*)d_in[2];
    const float* g1a = (const float*)d_in[3];
    const float* b1a = (const float*)d_in[4];
    const float* w3  = (const float*)d_in[5];
    const float* g3  = (const float*)d_in[6];
    const float* b3  = (const float*)d_in[7];
    const float* w1b = (const float*)d_in[8];
    const float* g1b = (const float*)d_in[9];
    const float* b1b = (const float*)d_in[10];
    float* out = (float*)d_out;
    float* ws  = (float*)d_ws;

    const int n = in_sizes[0] / CIN;   // 150000

    // ws layout: stats[192] (pad 256 f32) | w1at | w3img | w1bt | t1 | ybuf | [zb]
    float* stats = ws;
    u16* w1at  = (u16*)(ws + 256);
    u16* w3img = w1at + 16384;
    u16* w1bt  = w3img + 110592;
    u16* t1    = w1bt + 16384;
    u16* ybuf  = t1 + (size_t)n * CB;
    u16* zb    = nullptr;
    {
        size_t need = 1024 + 286720 + (size_t)n * CB * 4 + (size_t)n * COUT * 2;
        if (ws_size >= need) zb = ybuf + (size_t)n * CB;
    }

    hipMemsetAsync(stats, 0, 192 * sizeof(float), stream);

    const int nb64  = (n + 63) / 64;
    const int nb256 = (n + 255) / 256;
    k_prep<<<560, 256, 0, stream>>>(w1a, w3, w1b, w1at, w3img, w1bt);
    k_gemm1<<<nb256, 256, 0, stream>>>(data, w1at, t1, stats, n);
    k_apply64<<<2048, 256, 0, stream>>>(t1, stats, g1a, b1a, n);
    k_conv<<<nb64, 256, 0, stream>>>(t1, neigh, w3img, ybuf, stats, n);
    k_gemm2<<<dim3(nb256, 4), 256, 0, stream>>>(ybuf, w1bt, out, zb, stats, g3, b3, n);
    if (zb)
        k_final_bf<<<2048, 256, 0, stream>>>(out, zb, data, stats + 128, g1b, b1b, n);
    else
        k_final<<<2048, 256, 0, stream>>>(out, data, stats + 128, g1b, b1b, n);
}

// Round 6
// 292.639 us; speedup vs baseline: 2.9753x; 1.0119x over previous
//
#include <hip/hip_runtime.h>
#include <math.h>

#define CIN 256
#define CB 64
#define COUT 256
#define KNB 27
#define EPS 1e-5f

typedef unsigned short u16;
typedef __attribute__((ext_vector_type(8))) short short8;
typedef __attribute__((ext_vector_type(4))) float f32x4;

typedef const __attribute__((address_space(1))) unsigned int* gas_u32p;
typedef __attribute__((address_space(3))) unsigned int* las_u32p;
// async global->LDS, 16B per lane, dest = wave-uniform base + lane*16
#define GLL(g, p) __builtin_amdgcn_global_load_lds((gas_u32p)(const void*)(g), \
        (las_u32p)(void*)(p), 16, 0, 0)

__device__ inline short f2bf(float f) {
    union { float f; unsigned u; } v; v.f = f;
    unsigned r = v.u + 0x7fff + ((v.u >> 16) & 1);   // RNE
    return (short)(r >> 16);
}
__device__ inline float bf2f(short s) {
    union { unsigned u; float f; } v; v.u = ((unsigned)(u16)s) << 16;
    return v.f;
}
__device__ inline short8 pack8(float4 x0, float4 x1) {
    short8 r;
    r[0] = f2bf(x0.x); r[1] = f2bf(x0.y); r[2] = f2bf(x0.z); r[3] = f2bf(x0.w);
    r[4] = f2bf(x1.x); r[5] = f2bf(x1.y); r[6] = f2bf(x1.z); r[7] = f2bf(x1.w);
    return r;
}

// ---------------------------------------------------------------------------
// Weight prep: bf16 conversion + transposes (+ XOR-swizzled w3 LDS image)
// ---------------------------------------------------------------------------
__global__ void k_prep(const float* __restrict__ w1a, const float* __restrict__ w3,
                       const float* __restrict__ w1b, u16* __restrict__ w1at,
                       u16* __restrict__ w3img, u16* __restrict__ w1bt)
{
    int i = blockIdx.x * 256 + threadIdx.x;
    if (i < 16384) {
        int k = i >> 6, d = i & 63;
        w1at[d * 256 + k] = (u16)f2bf(w1a[i]);
    } else if (i < 126976) {
        int j = i - 16384;
        int k = j >> 12, c = (j >> 6) & 63, d = j & 63;
        w3img[(size_t)k * 4096 + d * 64 + (c ^ ((d & 7) << 3))] = (u16)f2bf(w3[j]);
    } else if (i < 143360) {
        int j = i - 126976;
        int c = j >> 8, d = j & 255;
        w1bt[d * 64 + c] = (u16)f2bf(w1b[j]);
    }
}

// ---------------------------------------------------------------------------
// GEMM1: t1[N,64](bf16) = data[N,256](f32->bf16) @ w1a ; GN1 stats
// ---------------------------------------------------------------------------
__global__ __launch_bounds__(256) void k_gemm1(const float* __restrict__ data,
        const u16* __restrict__ w1at, u16* __restrict__ t1,
        float* __restrict__ stats, int n)
{
    __shared__ float s_sum[32], s_sq[32];
    const int tid = threadIdx.x;
    if (tid < 32) { s_sum[tid] = 0.f; s_sq[tid] = 0.f; }
    __syncthreads();
    const int l = tid & 63, wv = tid >> 6;
    const int ll = l & 15, lh = l >> 4;
    const int rowbase = blockIdx.x * 256 + wv * 64;

    f32x4 acc[4][4] = {};
#pragma unroll
    for (int kc = 0; kc < 8; ++kc) {
        short8 b[4];
#pragma unroll
        for (int f = 0; f < 4; ++f)
            b[f] = *(const short8*)(w1at + (size_t)(f * 16 + ll) * 256 + kc * 32 + lh * 8);
#pragma unroll
        for (int rt = 0; rt < 4; ++rt) {
            int row = rowbase + rt * 16 + ll;
            int rowc = (row < n) ? row : 0;
            const float* ar = data + (size_t)rowc * CIN + kc * 32 + lh * 8;
            short8 a = pack8(*(const float4*)ar, *(const float4*)(ar + 4));
#pragma unroll
            for (int f = 0; f < 4; ++f)
                acc[rt][f] = __builtin_amdgcn_mfma_f32_16x16x32_bf16(a, b[f], acc[rt][f], 0, 0, 0);
        }
    }
    float gs[4] = {0.f, 0.f, 0.f, 0.f}, gq[4] = {0.f, 0.f, 0.f, 0.f};
#pragma unroll
    for (int rt = 0; rt < 4; ++rt) {
#pragma unroll
        for (int f = 0; f < 4; ++f) {
#pragma unroll
            for (int r = 0; r < 4; ++r) {
                int rr = rowbase + rt * 16 + lh * 4 + r;
                if (rr < n) {
                    float v = acc[rt][f][r];
                    t1[(size_t)rr * CB + f * 16 + ll] = (u16)f2bf(v);
                    gs[f] += v; gq[f] += v * v;
                }
            }
        }
    }
#pragma unroll
    for (int f = 0; f < 4; ++f) {
        float s = gs[f], q = gq[f];
        s += __shfl_xor(s, 1); s += __shfl_xor(s, 16); s += __shfl_xor(s, 32);
        q += __shfl_xor(q, 1); q += __shfl_xor(q, 16); q += __shfl_xor(q, 32);
        if ((l & 0x31) == 0) {
            atomicAdd(&s_sum[f * 8 + (ll >> 1)], s);
            atomicAdd(&s_sq [f * 8 + (ll >> 1)], q);
        }
    }
    __syncthreads();
    if (tid < 32) {
        atomicAdd(&stats[tid], s_sum[tid]);
        atomicAdd(&stats[32 + tid], s_sq[tid]);
    }
}

// ---------------------------------------------------------------------------
// GN apply + ReLU, in-place on a [N,64] bf16 buffer (2 channels per group)
// ---------------------------------------------------------------------------
__global__ void k_apply64(u16* __restrict__ buf, const float* __restrict__ st,
        const float* __restrict__ gamma, const float* __restrict__ beta, int n)
{
    const float cnt = (float)n * 2.0f;
    const int total = n * 8;
    for (int i = blockIdx.x * blockDim.x + threadIdx.x; i < total;
         i += gridDim.x * blockDim.x) {
        int c0 = (i & 7) * 8;
        short8 v = ((short8*)buf)[i];
#pragma unroll
        for (int j = 0; j < 8; ++j) {
            int c = c0 + j, g = c >> 1;
            float mu = st[g] / cnt;
            float var = st[32 + g] / cnt - mu * mu;
            float inv = rsqrtf(var + EPS);
            float x = bf2f(v[j]);
            x = fmaxf((x - mu) * inv * gamma[c] + beta[c], 0.f);
            v[j] = f2bf(x);
        }
        ((short8*)buf)[i] = v;
    }
}

// ---------------------------------------------------------------------------
// Octree conv (bf16 MFMA): y[n,d] = sum_k sum_c x[neigh[n,k],c] * w3[k,c,d]
// 128 nodes x 64 d per block, 4 waves (each 32 rows, acc[2][4], 16 MFMA/k).
// w3 staged via async global_load_lds (dbuf, no VGPR round-trip, no ds_write);
// per-lane gather prefetch (k+1) pinned above the MFMA cluster with
// sched_barrier(0). One __syncthreads per k (its vmcnt(0) drain is the only
// wait; loads have the whole MFMA cluster to land).
// ---------------------------------------------------------------------------
__global__ __launch_bounds__(256) void k_conv(const u16* __restrict__ xb,
        const int* __restrict__ neigh, const u16* __restrict__ w3img,
        u16* __restrict__ y, float* __restrict__ stats, int n)
{
    __shared__ u16 s_w3[2][4096];     // 2 x 8 KB swizzled [64d][64c] images
    __shared__ float s_sum[32], s_sq[32];
    const int tid = threadIdx.x;
    if (tid < 32) { s_sum[tid] = 0.f; s_sq[tid] = 0.f; }
    const int row0 = blockIdx.x * 128;
    const int l = tid & 63, wv = tid >> 6;
    const int ll = l & 15, lh = l >> 4;
    const int r0 = row0 + wv * 32 + ll;
    const int r1 = r0 + 16;
    const int r0c = (r0 < n) ? r0 : 0;
    const int r1c = (r1 < n) ? r1 : 0;
    const int* __restrict__ nrow0 = neigh + (size_t)r0c * KNB;
    const int* __restrict__ nrow1 = neigh + (size_t)r1c * KNB;

    // per-lane staging addresses: lane l covers bytes [wv*2048 + l*16) x2
    u16* ld0 = &s_w3[0][0] + wv * 1024 + l * 8;
    u16* ld1 = &s_w3[1][0] + wv * 1024 + l * 8;
    const u16* gw = w3img + wv * 1024 + l * 8;

    // prologue: stage w3[0] (async) + gather k=0
    GLL(gw, ld0);
    GLL(gw + 512, ld0 + 512);
    int ia = nrow0[0], ib = nrow1[0];
    {
        const u16* xa = xb + (size_t)ia * CB + lh * 8;
        const u16* xc = xb + (size_t)ib * CB + lh * 8;
        ia = nrow0[1]; ib = nrow1[1];
        // loads below overlap the GLL; consumed after the barrier
        __builtin_amdgcn_sched_barrier(0);
    }
    short8 a0c, a1c, a2c, a3c;
    {
        const u16* xa = xb + (size_t)nrow0[0] * CB + lh * 8;
        const u16* xc = xb + (size_t)nrow1[0] * CB + lh * 8;
        a0c = *(const short8*)xa; a1c = *(const short8*)(xa + 32);
        a2c = *(const short8*)xc; a3c = *(const short8*)(xc + 32);
    }
    __syncthreads();

    f32x4 acc[2][4] = {};
    for (int k = 0; k < KNB; ++k) {
        const int cur = k & 1;
        short8 a0n, a1n, a2n, a3n;
        if (k + 1 < KNB) {
            // stage w3[k+1] async into the other buffer
            const u16* gsrc = w3img + (size_t)(k + 1) * 4096 + wv * 1024 + l * 8;
            u16* ldst = cur ? ld0 : ld1;
            GLL(gsrc, ldst);
            GLL(gsrc + 512, ldst + 512);
            // gather prefetch k+1 (indices read per-lane, L1-hot)
            int i2 = nrow0[k + 1], i3 = nrow1[k + 1];
            const u16* xa = xb + (size_t)i2 * CB + lh * 8;
            const u16* xc = xb + (size_t)i3 * CB + lh * 8;
            a0n = *(const short8*)xa; a1n = *(const short8*)(xa + 32);
            a2n = *(const short8*)xc; a3n = *(const short8*)(xc + 32);
        }
        __builtin_amdgcn_sched_barrier(0);   // keep prefetch issue above MFMA
        // compute tile k: B frags shared across both row tiles
#pragma unroll
        for (int f = 0; f < 4; ++f) {
            int d = f * 16 + ll;
            int swz = (d & 7) << 4;
            short8 b0 = *(const short8*)((const char*)&s_w3[cur][0] + d * 128 + ((lh * 16) ^ swz));
            short8 b1 = *(const short8*)((const char*)&s_w3[cur][0] + d * 128 + ((64 + lh * 16) ^ swz));
            acc[0][f] = __builtin_amdgcn_mfma_f32_16x16x32_bf16(a0c, b0, acc[0][f], 0, 0, 0);
            acc[0][f] = __builtin_amdgcn_mfma_f32_16x16x32_bf16(a1c, b1, acc[0][f], 0, 0, 0);
            acc[1][f] = __builtin_amdgcn_mfma_f32_16x16x32_bf16(a2c, b0, acc[1][f], 0, 0, 0);
            acc[1][f] = __builtin_amdgcn_mfma_f32_16x16x32_bf16(a3c, b1, acc[1][f], 0, 0, 0);
        }
        if (k + 1 < KNB) { a0c = a0n; a1c = a1n; a2c = a2n; a3c = a3n; }
        __syncthreads();   // drains vmcnt -> next buffer + gathers complete
    }
    float gs[4] = {0.f, 0.f, 0.f, 0.f}, gq[4] = {0.f, 0.f, 0.f, 0.f};
#pragma unroll
    for (int rt = 0; rt < 2; ++rt) {
#pragma unroll
        for (int f = 0; f < 4; ++f) {
#pragma unroll
            for (int r = 0; r < 4; ++r) {
                int rr = row0 + wv * 32 + rt * 16 + lh * 4 + r;
                if (rr < n) {
                    float v = acc[rt][f][r];
                    y[(size_t)rr * CB + f * 16 + ll] = (u16)f2bf(v);
                    gs[f] += v; gq[f] += v * v;
                }
            }
        }
    }
#pragma unroll
    for (int f = 0; f < 4; ++f) {
        float s = gs[f], q = gq[f];
        s += __shfl_xor(s, 1); s += __shfl_xor(s, 16); s += __shfl_xor(s, 32);
        q += __shfl_xor(q, 1); q += __shfl_xor(q, 16); q += __shfl_xor(q, 32);
        if ((l & 0x31) == 0) {
            atomicAdd(&s_sum[f * 8 + (ll >> 1)], s);
            atomicAdd(&s_sq [f * 8 + (ll >> 1)], q);
        }
    }
    __syncthreads();
    if (tid < 32) {
        atomicAdd(&stats[64 + tid], s_sum[tid]);
        atomicAdd(&stats[96 + tid], s_sq[tid]);
    }
}

// ---------------------------------------------------------------------------
// GEMM2 with fused GN2-apply on the A path:
// z[N,256] = relu(gn2(y))[N,64](bf16) @ w1b ; GN3 stats.
// Stores bf16 into zb (if non-null) else f32 into z.
// ---------------------------------------------------------------------------
__global__ __launch_bounds__(256) void k_gemm2(const u16* __restrict__ y2,
        const u16* __restrict__ w1bt, float* __restrict__ z, u16* __restrict__ zb,
        float* __restrict__ stats, const float* __restrict__ g3,
        const float* __restrict__ b3, int n)
{
    __shared__ float s_sum[8], s_sq[8];
    const int tid = threadIdx.x;
    if (tid < 8) { s_sum[tid] = 0.f; s_sq[tid] = 0.f; }
    __syncthreads();
    const int l = tid & 63, wv = tid >> 6;
    const int ll = l & 15, lh = l >> 4;
    const int rowbase = blockIdx.x * 256 + wv * 64;
    const int cb = blockIdx.y;

    // per-lane GN2 scale/shift for the 16 k-channels this lane touches
    const float* st2 = stats + 64;
    const float cnt2 = (float)n * 2.0f;
    float sc[16], sh[16];
#pragma unroll
    for (int j = 0; j < 16; ++j) {
        int c = (j < 8) ? (lh * 8 + j) : (32 + lh * 8 + (j - 8));
        int g = c >> 1;
        float mu = st2[g] / cnt2;
        float var = st2[32 + g] / cnt2 - mu * mu;
        float inv = rsqrtf(var + EPS);
        float gm = g3[c];
        sc[j] = inv * gm;
        sh[j] = b3[c] - mu * inv * gm;
    }

    short8 b0[4], b1[4];
#pragma unroll
    for (int f = 0; f < 4; ++f) {
        const u16* br = w1bt + (size_t)(cb * 64 + f * 16 + ll) * CB + lh * 8;
        b0[f] = *(const short8*)(br);
        b1[f] = *(const short8*)(br + 32);
    }
    f32x4 acc[4][4] = {};
#pragma unroll
    for (int rt = 0; rt < 4; ++rt) {
        int row = rowbase + rt * 16 + ll;
        int rowc = (row < n) ? row : 0;
        const u16* ar = y2 + (size_t)rowc * CB + lh * 8;
        short8 r0 = *(const short8*)(ar);
        short8 r1 = *(const short8*)(ar + 32);
        short8 a0, a1;
#pragma unroll
        for (int j = 0; j < 8; ++j) {
            a0[j] = f2bf(fmaxf(bf2f(r0[j]) * sc[j] + sh[j], 0.f));
            a1[j] = f2bf(fmaxf(bf2f(r1[j]) * sc[8 + j] + sh[8 + j], 0.f));
        }
#pragma unroll
        for (int f = 0; f < 4; ++f) {
            acc[rt][f] = __builtin_amdgcn_mfma_f32_16x16x32_bf16(a0, b0[f], acc[rt][f], 0, 0, 0);
            acc[rt][f] = __builtin_amdgcn_mfma_f32_16x16x32_bf16(a1, b1[f], acc[rt][f], 0, 0, 0);
        }
    }
    float gs[4] = {0.f, 0.f, 0.f, 0.f}, gq[4] = {0.f, 0.f, 0.f, 0.f};
#pragma unroll
    for (int rt = 0; rt < 4; ++rt) {
#pragma unroll
        for (int f = 0; f < 4; ++f) {
#pragma unroll
            for (int r = 0; r < 4; ++r) {
                int rr = rowbase + rt * 16 + lh * 4 + r;
                if (rr < n) {
                    float v = acc[rt][f][r];
                    size_t off = (size_t)rr * COUT + cb * 64 + f * 16 + ll;
                    if (zb) zb[off] = (u16)f2bf(v); else z[off] = v;
                    gs[f] += v; gq[f] += v * v;
                }
            }
        }
    }
#pragma unroll
    for (int f = 0; f < 4; ++f) {
        float s = gs[f], q = gq[f];
        s += __shfl_xor(s, 1); s += __shfl_xor(s, 2); s += __shfl_xor(s, 4);
        s += __shfl_xor(s, 16); s += __shfl_xor(s, 32);
        q += __shfl_xor(q, 1); q += __shfl_xor(q, 2); q += __shfl_xor(q, 4);
        q += __shfl_xor(q, 16); q += __shfl_xor(q, 32);
        if ((l & 0x37) == 0) {
            atomicAdd(&s_sum[f * 2 + (ll >> 3)], s);
            atomicAdd(&s_sq [f * 2 + (ll >> 3)], q);
        }
    }
    __syncthreads();
    if (tid < 8) {
        atomicAdd(&stats[128 + cb * 8 + tid], s_sum[tid]);
        atomicAdd(&stats[160 + cb * 8 + tid], s_sq[tid]);
    }
}

// ---------------------------------------------------------------------------
// Final: out = relu(GN3(z) + data). bf16-z variant (z in ws).
// ---------------------------------------------------------------------------
__global__ void k_final_bf(float* __restrict__ out, const u16* __restrict__ zb,
        const float* __restrict__ data, const float* __restrict__ st,
        const float* __restrict__ gamma, const float* __restrict__ beta, int n)
{
    const float cnt = (float)n * 8.0f;
    const int total = n * 32;   // 8-channel chunks
    for (int i = blockIdx.x * blockDim.x + threadIdx.x; i < total;
         i += gridDim.x * blockDim.x) {
        int c0 = (i & 31) * 8;
        int g = c0 >> 3;
        float mu = st[g] / cnt;
        float var = st[32 + g] / cnt - mu * mu;
        float inv = rsqrtf(var + EPS);
        short8 zv = ((const short8*)zb)[i];
        float dd[8], oo[8];
        *(float4*)dd = *(const float4*)(data + (size_t)i * 8);
        *(float4*)(dd + 4) = *(const float4*)(data + (size_t)i * 8 + 4);
#pragma unroll
        for (int j = 0; j < 8; ++j)
            oo[j] = fmaxf((bf2f(zv[j]) - mu) * inv * gamma[c0 + j] + beta[c0 + j] + dd[j], 0.f);
        *(float4*)(out + (size_t)i * 8) = *(float4*)oo;
        *(float4*)(out + (size_t)i * 8 + 4) = *(float4*)(oo + 4);
    }
}

// f32-z fallback (z already in d_out), in-place
__global__ void k_final(float* __restrict__ zo, const float* __restrict__ data,
        const float* __restrict__ st, const float* __restrict__ gamma,
        const float* __restrict__ beta, int n)
{
    const float cnt = (float)n * 8.0f;
    const int total = n * (COUT / 4);
    for (int i = blockIdx.x * blockDim.x + threadIdx.x; i < total;
         i += gridDim.x * blockDim.x) {
        int c4 = (i & (COUT / 4 - 1)) * 4;
        int g = c4 >> 3;
        float mu = st[g] / cnt;
        float var = st[32 + g] / cnt - mu * mu;
        float inv = rsqrtf(var + EPS);
        float4 zv = *(float4*)(zo + (size_t)i * 4);
        float4 dv = *(const float4*)(data + (size_t)i * 4);
        zv.x = fmaxf((zv.x - mu) * inv * gamma[c4 + 0] + beta[c4 + 0] + dv.x, 0.f);
        zv.y = fmaxf((zv.y - mu) * inv * gamma[c4 + 1] + beta[c4 + 1] + dv.y, 0.f);
        zv.z = fmaxf((zv.z - mu) * inv * gamma[c4 + 2] + beta[c4 + 2] + dv.z, 0.f);
        zv.w = fmaxf((zv.w - mu) * inv * gamma[c4 + 3] + beta[c4 + 3] + dv.w, 0.f);
        *(float4*)(zo + (size_t)i * 4) = zv;
    }
}

// ---------------------------------------------------------------------------
extern "C" void kernel_launch(void* const* d_in, const int* in_sizes, int n_in,
                              void* d_out, int out_size, void* d_ws, size_t ws_size,
                              hipStream_t stream)
{
    const float* data = (const float*)d_in[0];
    const int*   neigh = (const int*)d_in[1];
    const float* w1a = (const float*)d_in[2];
    const float* g1a = (const float*)d_in[3];
    const float* b1a = (const float*)d_in[4];
    const float* w3  = (const float*)d_in[5];
    const float* g3  = (const float*)d_in[6];
    const float* b3  = (const float*)d_in[7];
    const float* w1b = (const float*)d_in[8];
    const float* g1b = (const float*)d_in[9];
    const float* b1b = (const float*)d_in[10];
    float* out = (float*)d_out;
    float* ws  = (float*)d_ws;

    const int n = in_sizes[0] / CIN;   // 150000

    // ws layout: stats[192] (pad 256 f32) | w1at | w3img | w1bt | t1 | ybuf | [zb]
    float* stats = ws;
    u16* w1at  = (u16*)(ws + 256);
    u16* w3img = w1at + 16384;
    u16* w1bt  = w3img + 110592;
    u16* t1    = w1bt + 16384;
    u16* ybuf  = t1 + (size_t)n * CB;
    u16* zb    = nullptr;
    {
        size_t need = 1024 + 286720 + (size_t)n * CB * 4 + (size_t)n * COUT * 2;
        if (ws_size >= need) zb = ybuf + (size_t)n * CB;
    }

    hipMemsetAsync(stats, 0, 192 * sizeof(float), stream);

    const int nb128 = (n + 127) / 128;
    const int nb256 = (n + 255) / 256;
    k_prep<<<560, 256, 0, stream>>>(w1a, w3, w1b, w1at, w3img, w1bt);
    k_gemm1<<<nb256, 256, 0, stream>>>(data, w1at, t1, stats, n);
    k_apply64<<<2048, 256, 0, stream>>>(t1, stats, g1a, b1a, n);
    k_conv<<<nb128, 256, 0, stream>>>(t1, neigh, w3img, ybuf, stats, n);
    k_gemm2<<<dim3(nb256, 4), 256, 0, stream>>>(ybuf, w1bt, out, zb, stats, g3, b3, n);
    if (zb)
        k_final_bf<<<2048, 256, 0, stream>>>(out, zb, data, stats + 128, g1b, b1b, n);
    else
        k_final<<<2048, 256, 0, stream>>>(out, data, stats + 128, g1b, b1b, n);
}